// Round 4
// baseline (978.694 us; speedup 1.0000x reference)
//
#include <hip/hip_runtime.h>
#include <stdint.h>

// ============================================================================
// PopularNicheGraphBuilder: segment-sums -> normalize -> per-row db3 DWT stats
// (in LDS) -> exact replication of jax.random.beta (threefry + Marsaglia-Tsang
// log-space gamma).
//
// Round 4: level-1 DWT computed SPARSELY from the sorted winner entry list
// (owner-centric scan; bit-exact vs dense: skipped terms are exact +/-0.0 and
// per-thread accumulation order is preserved). Dense x buffer eliminated ->
// LDS 69->38 KB (items, 4 blocks/CU) and 35->20 KB (users, 8 blocks/CU).
// Levels 2-3 stay dense in-place with 8-way ILP (same per-thread j-order).
// ============================================================================
#define PARTITIONABLE 1

typedef unsigned long long ull;

#define NUM_U 16384
#define NUM_I 8192
#define CAP_U 160
#define CAP_I 256

// output layout
#define OFF_UPW 0
#define OFF_UMW 16384
#define OFF_IPW 32768
#define OFF_IMW 40960
#define OFF_ACT 49152
#define OFF_POP 65536

// ---------------- threefry2x32 ----------------
struct K2 { uint32_t a, b; };

__host__ __device__ inline void tf2x32(uint32_t k0, uint32_t k1, uint32_t& x0, uint32_t& x1) {
  const uint32_t ks2 = k0 ^ k1 ^ 0x1BD11BDAu;
  x0 += k0; x1 += k1;
#define TF_R(r) { x0 += x1; x1 = (x1 << (r)) | (x1 >> (32 - (r))); x1 ^= x0; }
  TF_R(13) TF_R(15) TF_R(26) TF_R(6)
  x0 += k1; x1 += ks2 + 1u;
  TF_R(17) TF_R(29) TF_R(16) TF_R(24)
  x0 += ks2; x1 += k0 + 2u;
  TF_R(13) TF_R(15) TF_R(26) TF_R(6)
  x0 += k0; x1 += k1 + 3u;
  TF_R(17) TF_R(29) TF_R(16) TF_R(24)
  x0 += k1; x1 += ks2 + 4u;
  TF_R(13) TF_R(15) TF_R(26) TF_R(6)
  x0 += ks2; x1 += k0 + 5u;
#undef TF_R
}

__host__ __device__ inline K2 tf_enc(K2 k, uint32_t x0, uint32_t x1) {
  tf2x32(k.a, k.b, x0, x1);
  K2 r; r.a = x0; r.b = x1; return r;
}

// split(key) -> 2 children
__host__ __device__ inline void split2(K2 k, K2& c0, K2& c1) {
#if PARTITIONABLE
  c0 = tf_enc(k, 0u, 0u);
  c1 = tf_enc(k, 0u, 1u);
#else
  K2 p = tf_enc(k, 0u, 2u);
  K2 q = tf_enc(k, 1u, 3u);
  c0.a = p.a; c0.b = q.a;
  c1.a = p.b; c1.b = q.b;
#endif
}

// split(key, 3)
__device__ inline void split3(K2 k, K2& c0, K2& c1, K2& c2) {
#if PARTITIONABLE
  c0 = tf_enc(k, 0u, 0u);
  c1 = tf_enc(k, 0u, 1u);
  c2 = tf_enc(k, 0u, 2u);
#else
  K2 p = tf_enc(k, 0u, 3u);
  K2 q = tf_enc(k, 1u, 4u);
  K2 r = tf_enc(k, 2u, 5u);
  c0.a = p.a; c0.b = q.a;
  c1.a = r.a; c1.b = p.b;
  c2.a = q.b; c2.b = r.b;
#endif
}

// scalar random_bits(key, 32, ())
__device__ inline uint32_t draw_bits(K2 k) {
  K2 e = tf_enc(k, 0u, 0u);
#if PARTITIONABLE
  return e.a ^ e.b;
#else
  return e.a;
#endif
}

// split(key, B)[i]
__device__ inline K2 elem_key(K2 k, uint32_t i, uint32_t B) {
#if PARTITIONABLE
  return tf_enc(k, 0u, i);
#else
  if (i < (B >> 1)) {
    K2 p = tf_enc(k, 2u * i, B + 2u * i);
    K2 q = tf_enc(k, 2u * i + 1u, B + 2u * i + 1u);
    K2 r; r.a = p.a; r.b = q.a; return r;
  } else {
    uint32_t j = 2u * i - B;
    K2 p = tf_enc(k, j, 2u * i);
    K2 q = tf_enc(k, j + 1u, 2u * i + 1u);
    K2 r; r.a = p.b; r.b = q.b; return r;
  }
#endif
}

__device__ inline float u01_bits(uint32_t b) {
  return __uint_as_float((b >> 9) | 0x3F800000u) - 1.0f;
}

// XLA ErfInv32 (Giles polynomial) -- matches lax.erf_inv on f32
__device__ inline float erfinv_f32(float x) {
  float w = -log1pf(-x * x);
  float p;
  if (w < 5.0f) {
    w = w - 2.5f;
    p = 2.81022636e-08f;
    p = fmaf(p, w, 3.43273939e-07f);
    p = fmaf(p, w, -3.5233877e-06f);
    p = fmaf(p, w, -4.39150654e-06f);
    p = fmaf(p, w, 0.00021858087f);
    p = fmaf(p, w, -0.00125372503f);
    p = fmaf(p, w, -0.00417768164f);
    p = fmaf(p, w, 0.246640727f);
    p = fmaf(p, w, 1.50140941f);
  } else {
    w = sqrtf(w) - 3.0f;
    p = -0.000200214257f;
    p = fmaf(p, w, 0.000100950558f);
    p = fmaf(p, w, 0.00134934322f);
    p = fmaf(p, w, -0.00367342844f);
    p = fmaf(p, w, 0.00573950773f);
    p = fmaf(p, w, -0.0076224613f);
    p = fmaf(p, w, 0.00943887047f);
    p = fmaf(p, w, 1.00167406f);
    p = fmaf(p, w, 2.83297682f);
  }
  return p * x;
}

// jax _gamma_one with log_space=True (Marsaglia-Tsang + boost)
__device__ float log_gamma_sample(K2 key, float alpha_orig) {
  const bool boost = (alpha_orig >= 1.0f);
  const float alpha = boost ? alpha_orig : (alpha_orig + 1.0f);
  const float d = alpha - 0.33333334f;
  const float c = 0.33333334f / sqrtf(d);

  K2 k0, sub;
  split2(key, k0, sub);
  const float u_boost = u01_bits(draw_bits(sub));

  K2 kcur = k0;
  float X = 0.0f, V = 1.0f, U = 2.0f;
  while ((U >= 1.0f - 0.0331f * (X * X)) &&
         (logf(U) >= X * 0.5f + d * ((1.0f - V) + logf(V)))) {
    K2 knext, xk, Uk;
    split3(kcur, knext, xk, Uk);
    kcur = knext;
    float x, v;
    K2 ik = xk;
    do {
      K2 in0, isub;
      split2(ik, in0, isub);
      ik = in0;
      float f = u01_bits(draw_bits(isub));
      // uniform(lo=nextafter(-1,0), hi=1): (hi-lo) rounds to exactly 2.0f
      float u = fmaxf(-0.99999994f, f * 2.0f + (-0.99999994f));
      x = 1.41421356f * erfinv_f32(u);   // sqrt(2) as f32
      v = 1.0f + x * c;
    } while (v <= 0.0f);
    X = x * x;
    V = (v * v) * v;
    U = u01_bits(draw_bits(Uk));
  }
  float lg = logf(d * V);
  if (!boost) lg += log1pf(-u_boost) / alpha_orig;
  return lg;
}

// ---------------- pipeline kernels ----------------

__global__ __launch_bounds__(256) void zero_kernel(ull* p, int n) {
  int i = blockIdx.x * 256 + threadIdx.x;
  if (i < n) p[i] = 0ull;
}

// counts + fixed-point value sums per item, plus CSR-ish fill of both sides
__global__ __launch_bounds__(256) void count_fill_kernel(
    const int* __restrict__ user, const int* __restrict__ item,
    const float* __restrict__ val, int n,
    int* __restrict__ cnt, ull* __restrict__ sv,
    int* __restrict__ fu, int* __restrict__ fi,
    uint32_t* __restrict__ lu, uint32_t* __restrict__ li) {
  for (int k = blockIdx.x * 256 + threadIdx.x; k < n; k += gridDim.x * 256) {
    int it = item[k];
    atomicAdd(&cnt[it], 1);
    atomicAdd(&sv[it], (ull)llrintf(val[k] * 4294967296.0f));  // fixed-point 2^32
    int q = atomicAdd(&fi[it], 1);
    if (q < CAP_I) li[(size_t)it * CAP_I + q] = (uint32_t)k;
    int u = user[k];
    int p = atomicAdd(&fu[u], 1);
    if (p < CAP_U) lu[(size_t)u * CAP_U + p] = (uint32_t)k;
  }
}

__global__ __launch_bounds__(256) void pop_raw_kernel(const int* __restrict__ cnt,
                                                      const ull* __restrict__ sv,
                                                      float* __restrict__ pop,
                                                      double* __restrict__ nrm2) {
  __shared__ float red[4];
  int i = blockIdx.x * 256 + threadIdx.x;
  float p = 0.0f;
  if (i < NUM_I) {
    float svf = (float)((double)sv[i] * (1.0 / 4294967296.0));
    p = svf * log1pf((float)cnt[i]);
    pop[i] = p;
  }
  float sq = p * p;
  for (int o = 32; o > 0; o >>= 1) sq += __shfl_down(sq, o);
  if ((threadIdx.x & 63) == 0) red[threadIdx.x >> 6] = sq;
  __syncthreads();
  if (threadIdx.x == 0) atomicAdd(nrm2, (double)(red[0] + red[1] + red[2] + red[3]));
}

__global__ __launch_bounds__(256) void pop_norm_kernel(float* __restrict__ pop,
                                                       const double* __restrict__ nrm2,
                                                       float* __restrict__ out) {
  int i = blockIdx.x * 256 + threadIdx.x;
  if (i < NUM_I) {
    float nrm = sqrtf((float)(*nrm2));
    float v = pop[i] / (nrm + 1e-8f);
    pop[i] = v;
    out[OFF_POP + i] = v;
  }
}

__global__ __launch_bounds__(256) void act_accum_kernel(const int* __restrict__ user,
                                                        const int* __restrict__ item,
                                                        const float* __restrict__ val, int n,
                                                        const float* __restrict__ pop,
                                                        ull* __restrict__ acc) {
  for (int k = blockIdx.x * 256 + threadIdx.x; k < n; k += gridDim.x * 256) {
    float term = val[k] / log1pf(pop[item[k]] + 1e-8f);
    atomicAdd(&acc[user[k]], (ull)llrintf(term * 16777216.0f));  // fixed-point 2^24
  }
}

__global__ __launch_bounds__(256) void act_pre_kernel(const ull* __restrict__ acc,
                                                      float* __restrict__ act,
                                                      double* __restrict__ nrm2) {
  __shared__ float red[4];
  int u = blockIdx.x * 256 + threadIdx.x;
  float a = 0.0f;
  if (u < NUM_U) {
    a = (float)((double)acc[u] * (1.0 / 16777216.0));
    act[u] = a;
  }
  float sq = a * a;
  for (int o = 32; o > 0; o >>= 1) sq += __shfl_down(sq, o);
  if ((threadIdx.x & 63) == 0) red[threadIdx.x >> 6] = sq;
  __syncthreads();
  if (threadIdx.x == 0) atomicAdd(nrm2, (double)(red[0] + red[1] + red[2] + red[3]));
}

__global__ __launch_bounds__(256) void act_norm_kernel(float* __restrict__ act,
                                                       const double* __restrict__ nrm2,
                                                       float* __restrict__ out) {
  int u = blockIdx.x * 256 + threadIdx.x;
  if (u < NUM_U) {
    float nrm = sqrtf((float)(*nrm2));
    float v = act[u] / (nrm + 1e-8f);
    act[u] = v;
    out[OFF_ACT + u] = v;
  }
}

// One in-place DWT analysis level over the padded LDS buffer (8-way ILP).
// Data element i lives at buf[4+i]; front pad 4 always zero. Input data
// [0..NIN-1]; output overwrites data [0..MOUT-1]. In-place safety: batch b
// reads positions >= 4096b-4, batch b-1 writes <= 2048b-1 (disjoint for b>=1);
// within a batch, all reads precede the barrier, writes follow. Per-thread
// position order (m = tid + 256j, j ascending) identical to rounds 1-3.
template <int MOUT, bool LAST>
__device__ inline void dwt_level_inplace8(float* __restrict__ buf, int tid,
                                          float& h_acc, float& lo_acc) {
  for (int base = 0; base < MOUT; base += 2048) {
    float lov[8], hiv[8];
    int mv[8]; bool okv[8];
#pragma unroll
    for (int u = 0; u < 8; ++u) {
      int m = base + tid + (u << 8);
      bool ok = m < MOUT;
      mv[u] = m; okv[u] = ok;
      int mm = ok ? m : (MOUT - 1);
      const float* s = buf + 2 * mm + 5;   // s[-t] == data[2*mm+1-t]
      float x0 = s[0], x1 = s[-1], x2 = s[-2], x3 = s[-3], x4 = s[-4], x5 = s[-5];
      float lo = 0.0f, hi = 0.0f;
      lo += 0.035226291882100656f * x0;  hi += -0.3326705529509569f * x0;
      lo += -0.08544127388224149f * x1;  hi += 0.8068915093133388f * x1;
      lo += -0.13501102001039084f * x2;  hi += -0.4598775021193313f * x2;
      lo += 0.4598775021193313f * x3;    hi += -0.13501102001039084f * x3;
      lo += 0.8068915093133388f * x4;    hi += 0.08544127388224149f * x4;
      lo += 0.3326705529509569f * x5;    hi += 0.035226291882100656f * x5;
      lov[u] = lo; hiv[u] = hi;
    }
    if (!LAST) __syncthreads();
#pragma unroll
    for (int u = 0; u < 8; ++u) {
      if (okv[u]) {
        if (!LAST) buf[4 + mv[u]] = lov[u];
        else lo_acc += lov[u];
        h_acc += hiv[u] * hiv[u];
      }
    }
  }
}

// per-row 3-level db3 DWT stats. Level 1 computed sparsely from the sorted
// winner entry list (owner-centric: thread t owns positions m == t mod 256,
// matching the dense kernels' ownership); levels 2-3 dense in-place.
template <int M1, int M2, int M3, int CAP>
__global__ __launch_bounds__(256) void dwt_rows_kernel(
    const uint32_t* __restrict__ klist, const int* __restrict__ rowlen,
    const int* __restrict__ colsrc, const float* __restrict__ values,
    const float* __restrict__ scale_vec,
    float* __restrict__ low_out, float* __restrict__ high_out) {
  extern __shared__ float smem[];
  float* buf = smem;                       // M1 + 12 (data at +4)
  float* ev = buf + (M1 + 12);             // CAP raw scaled values
  float* sval = ev + CAP;                  // CAP sorted winner values
  int* ecol = (int*)(sval + CAP);          // CAP raw cols
  int* ek = ecol + CAP;                    // CAP raw original indices
  int* win = ek + CAP;                     // CAP winner flags
  float* red = (float*)(win + CAP);        // 16
  int* s_nw = (int*)(red + 16);            // 1
  int* scol = ek;                          // sorted cols ALIAS ek (dead after pass1)

  const int r = blockIdx.x;
  const int tid = threadIdx.x;
  const float scale = 1.0f + scale_vec[r];
  int n = rowlen[r];
  if (n > CAP) n = CAP;

  for (int i = tid; i < M1 + 12; i += 256) buf[i] = 0.0f;
  for (int e = tid; e < n; e += 256) {
    uint32_t k = klist[(size_t)r * CAP + e];
    ecol[e] = colsrc[k];
    ek[e] = (int)k;
    ev[e] = values[k] * scale;
  }
  if (tid == 0) *s_nw = 0;
  __syncthreads();

  // pass 1: winner flags (entry with max original index wins -- XLA scatter)
  for (int e = tid; e < n; e += 256) {
    int c = ecol[e], kk = ek[e];
    int wf = 1;
    for (int j = 0; j < n; ++j)
      if (ecol[j] == c && ek[j] > kk) { wf = 0; break; }
    win[e] = wf;
  }
  __syncthreads();
  // pass 2: rank among winners (unique cols) -> sorted scatter
  for (int e = tid; e < n; e += 256) {
    if (win[e]) {
      int c = ecol[e];
      int rank = 0;
      for (int j = 0; j < n; ++j)
        rank += (win[j] && (ecol[j] < c)) ? 1 : 0;
      scol[rank] = c;        // scol aliases ek; pass 2 reads only ecol/win/ev
      sval[rank] = ev[e];
      atomicAdd(s_nw, 1);
    }
  }
  __syncthreads();
  const int nw = *s_nw;

  // ---- sparse level 1: owner-centric scan over sorted winner entries ----
  // Entry at col p touches m in [p>>1, (p>>1)+2] with tap t = 2m+1-p.
  // Thread t owns m == t (mod 256). Windows are monotone in p, so a thread's
  // touched m's arrive ascending and contiguously -> single current-window
  // register state. Tap accumulation order (t=0..5) and per-thread m order
  // match the dense kernel exactly; untouched positions contribute exact
  // +/-0.0 terms (identity), so results are bit-identical to the dense level.
  float h1 = 0.0f;
  {
    int m_cur = -1;
    float tv0 = 0.0f, tv1 = 0.0f, tv2 = 0.0f, tv3 = 0.0f, tv4 = 0.0f, tv5 = 0.0f;
    auto flush = [&]() {
      float lo = 0.0f, hi = 0.0f;
      lo += 0.035226291882100656f * tv0;  hi += -0.3326705529509569f * tv0;
      lo += -0.08544127388224149f * tv1;  hi += 0.8068915093133388f * tv1;
      lo += -0.13501102001039084f * tv2;  hi += -0.4598775021193313f * tv2;
      lo += 0.4598775021193313f * tv3;    hi += -0.13501102001039084f * tv3;
      lo += 0.8068915093133388f * tv4;    hi += 0.08544127388224149f * tv4;
      lo += 0.3326705529509569f * tv5;    hi += 0.035226291882100656f * tv5;
      buf[4 + m_cur] = lo;
      h1 += hi * hi;
    };
    for (int e = 0; e < nw; ++e) {
      int p = scol[e];
      float v = sval[e];
      int mlo = p >> 1;
      int rr = (tid - mlo) & 255;
      if (rr <= 2) {
        int m = mlo + rr;                  // owned position; m < M1 guaranteed
        if (m != m_cur) {
          if (m_cur >= 0) flush();
          m_cur = m;
          tv0 = tv1 = tv2 = tv3 = tv4 = tv5 = 0.0f;
        }
        int tt = 2 * m + 1 - p;            // tap index 0..5
        if      (tt == 0) tv0 = v;
        else if (tt == 1) tv1 = v;
        else if (tt == 2) tv2 = v;
        else if (tt == 3) tv3 = v;
        else if (tt == 4) tv4 = v;
        else              tv5 = v;
      }
    }
    if (m_cur >= 0) flush();
  }
  __syncthreads();

  // ---- dense levels 2-3, in place over buf ----
  float h2 = 0.0f, h3 = 0.0f, slo = 0.0f;
  float dummy = 0.0f;
  dwt_level_inplace8<M2, false>(buf, tid, h2, dummy);
  __syncthreads();
  // zero the stale gap read by level 3 (data [M2 .. M2+7])
  if (tid < 8) buf[4 + M2 + tid] = 0.0f;
  __syncthreads();
  dwt_level_inplace8<M3, true>(buf, tid, h3, slo);

  for (int o = 32; o > 0; o >>= 1) {
    h1 += __shfl_down(h1, o);
    h2 += __shfl_down(h2, o);
    h3 += __shfl_down(h3, o);
    slo += __shfl_down(slo, o);
  }
  int w = tid >> 6, lane = tid & 63;
  if (lane == 0) { red[w] = h1; red[4 + w] = h2; red[8 + w] = h3; red[12 + w] = slo; }
  __syncthreads();
  if (tid == 0) {
    float s1 = red[0] + red[1] + red[2] + red[3];
    float s2 = red[4] + red[5] + red[6] + red[7];
    float s3 = red[8] + red[9] + red[10] + red[11];
    float sl = red[12] + red[13] + red[14] + red[15];
    low_out[r] = sl / (float)M3;
    high_out[r] = sqrtf(s1) + sqrtf(s2) + sqrtf(s3);
  }
}

__global__ __launch_bounds__(256) void beta_kernel(
    const float* __restrict__ u_low, const float* __restrict__ u_high,
    const float* __restrict__ i_low, const float* __restrict__ i_high,
    float* __restrict__ out, K2 kAu, K2 kBu, K2 kAi, K2 kBi) {
  int t = blockIdx.x * 256 + threadIdx.x;
  if (t >= NUM_U + NUM_I) return;
  float low, high;
  K2 ka, kb;
  int o0, o1;
  if (t < NUM_U) {
    low = u_low[t]; high = u_high[t];
    ka = elem_key(kAu, (uint32_t)t, (uint32_t)NUM_U);
    kb = elem_key(kBu, (uint32_t)t, (uint32_t)NUM_U);
    o0 = OFF_UPW + t; o1 = OFF_UMW + t;
  } else {
    int j = t - NUM_U;
    low = i_low[j]; high = i_high[j];
    ka = elem_key(kAi, (uint32_t)j, (uint32_t)NUM_I);
    kb = elem_key(kBi, (uint32_t)j, (uint32_t)NUM_I);
    o0 = OFF_IPW + j; o1 = OFF_IMW + j;
  }
  float a1 = fmaxf(low, 1e-6f);
  float a2 = fmaxf(high, 1e-6f);
  float s = a1 + a2;
  a1 = a1 / s;
  a2 = a2 / s;
  float lga = log_gamma_sample(ka, 10.0f * a1);
  float lgb = log_gamma_sample(kb, 10.0f * a2);
  float m = fmaxf(lga, lgb);
  float na = expf(lga - m);
  float nb = expf(lgb - m);
  float w = na / (na + nb);
  out[o0] = w;
  out[o1] = 1.0f - w;
}

// ---------------- host ----------------
extern "C" void kernel_launch(void* const* d_in, const int* in_sizes, int n_in,
                              void* d_out, int out_size, void* d_ws, size_t ws_size,
                              hipStream_t stream) {
  const int* user_idx = (const int*)d_in[0];
  const int* item_idx = (const int*)d_in[1];
  const float* values = (const float*)d_in[2];
  const int NNZ = in_sizes[0];

  char* ws = (char*)d_ws;
  double* nrm2_pop = (double*)(ws + 0);
  double* nrm2_act = (double*)(ws + 8);
  ull* sv_acc = (ull*)(ws + 16);
  ull* act_acc = (ull*)(ws + 65552);
  int* cnt_i = (int*)(ws + 196624);
  float* pop = (float*)(ws + 229392);
  float* act = (float*)(ws + 262160);
  int* fill_u = (int*)(ws + 327696);
  int* fill_i = (int*)(ws + 393232);
  float* u_low = (float*)(ws + 426000);
  float* u_high = (float*)(ws + 491536);
  float* i_low = (float*)(ws + 557072);
  float* i_high = (float*)(ws + 589840);
  uint32_t* klist_u = (uint32_t*)(ws + 622608);
  uint32_t* klist_i = (uint32_t*)(ws + 11108368);
  float* out = (float*)d_out;

  // host-side key derivation: root=key(42)=(0,42); ku,ki=split(root); then
  // (key_a,key_b)=split(k) inside beta for each side.
  K2 root; root.a = 0u; root.b = 42u;
  K2 ku, ki, kAu, kBu, kAi, kBi;
  split2(root, ku, ki);
  split2(ku, kAu, kBu);
  split2(ki, kAi, kBi);

  const int zero_words = 622608 / 8;
  zero_kernel<<<(zero_words + 255) / 256, 256, 0, stream>>>((ull*)ws, zero_words);
  count_fill_kernel<<<1024, 256, 0, stream>>>(user_idx, item_idx, values, NNZ,
                                              cnt_i, sv_acc, fill_u, fill_i, klist_u, klist_i);
  pop_raw_kernel<<<NUM_I / 256, 256, 0, stream>>>(cnt_i, sv_acc, pop, nrm2_pop);
  pop_norm_kernel<<<NUM_I / 256, 256, 0, stream>>>(pop, nrm2_pop, out);
  act_accum_kernel<<<1024, 256, 0, stream>>>(user_idx, item_idx, values, NNZ, pop, act_acc);
  act_pre_kernel<<<NUM_U / 256, 256, 0, stream>>>(act_acc, act, nrm2_act);
  act_norm_kernel<<<NUM_U / 256, 256, 0, stream>>>(act, nrm2_act, out);

  // users: M1=4098 -> buf 4110 f; + 5*CAP + 17 -> ~19.7 KB, 8 blocks/CU
  constexpr int U_SHM = ((4098 + 12) + 5 * CAP_U + 17) * 4;
  // items: M1=8194 -> buf 8206 f; + 5*CAP + 17 -> ~38.0 KB, 4 blocks/CU
  constexpr int I_SHM = ((8194 + 12) + 5 * CAP_I + 17) * 4;
  hipFuncSetAttribute((const void*)dwt_rows_kernel<4098, 2051, 1028, CAP_U>,
                      hipFuncAttributeMaxDynamicSharedMemorySize, U_SHM);
  hipFuncSetAttribute((const void*)dwt_rows_kernel<8194, 4099, 2052, CAP_I>,
                      hipFuncAttributeMaxDynamicSharedMemorySize, I_SHM);

  dwt_rows_kernel<4098, 2051, 1028, CAP_U><<<NUM_U, 256, U_SHM, stream>>>(
      klist_u, fill_u, item_idx, values, act, u_low, u_high);
  dwt_rows_kernel<8194, 4099, 2052, CAP_I><<<NUM_I, 256, I_SHM, stream>>>(
      klist_i, fill_i, user_idx, values, pop, i_low, i_high);

  beta_kernel<<<(NUM_U + NUM_I + 255) / 256, 256, 0, stream>>>(
      u_low, u_high, i_low, i_high, out, kAu, kBu, kAi, kBi);
}

// Round 5
// 912.660 us; speedup vs baseline: 1.0724x; 1.0724x over previous
//
#include <hip/hip_runtime.h>
#include <stdint.h>

// ============================================================================
// PopularNicheGraphBuilder: segment-sums -> normalize -> per-row db3 DWT stats
// (in LDS) -> exact replication of jax.random.beta (threefry + Marsaglia-Tsang
// log-space gamma).
//
// Round 5: level-1 DWT is output-centric sparse: a column bitmap + popcount
// rank prefix (aliased over dead sort scratch) gives an O(1) "window empty?"
// test per output position; ~95% of positions cost ~6 ops, touched positions
// gather their <=6 taps in exact dense t-order (bit-identical numerics).
// LDS: items 39.0 KB (4 blocks/CU), users 20.3 KB (8 blocks/CU, 100% occ).
// Levels 2-3 dense in-place 8-way ILP (unchanged from round 4).
// ============================================================================
#define PARTITIONABLE 1

typedef unsigned long long ull;

#define NUM_U 16384
#define NUM_I 8192
#define CAP_U 160
#define CAP_I 256

// output layout
#define OFF_UPW 0
#define OFF_UMW 16384
#define OFF_IPW 32768
#define OFF_IMW 40960
#define OFF_ACT 49152
#define OFF_POP 65536

// ---------------- threefry2x32 ----------------
struct K2 { uint32_t a, b; };

__host__ __device__ inline void tf2x32(uint32_t k0, uint32_t k1, uint32_t& x0, uint32_t& x1) {
  const uint32_t ks2 = k0 ^ k1 ^ 0x1BD11BDAu;
  x0 += k0; x1 += k1;
#define TF_R(r) { x0 += x1; x1 = (x1 << (r)) | (x1 >> (32 - (r))); x1 ^= x0; }
  TF_R(13) TF_R(15) TF_R(26) TF_R(6)
  x0 += k1; x1 += ks2 + 1u;
  TF_R(17) TF_R(29) TF_R(16) TF_R(24)
  x0 += ks2; x1 += k0 + 2u;
  TF_R(13) TF_R(15) TF_R(26) TF_R(6)
  x0 += k0; x1 += k1 + 3u;
  TF_R(17) TF_R(29) TF_R(16) TF_R(24)
  x0 += k1; x1 += ks2 + 4u;
  TF_R(13) TF_R(15) TF_R(26) TF_R(6)
  x0 += ks2; x1 += k0 + 5u;
#undef TF_R
}

__host__ __device__ inline K2 tf_enc(K2 k, uint32_t x0, uint32_t x1) {
  tf2x32(k.a, k.b, x0, x1);
  K2 r; r.a = x0; r.b = x1; return r;
}

// split(key) -> 2 children
__host__ __device__ inline void split2(K2 k, K2& c0, K2& c1) {
#if PARTITIONABLE
  c0 = tf_enc(k, 0u, 0u);
  c1 = tf_enc(k, 0u, 1u);
#else
  K2 p = tf_enc(k, 0u, 2u);
  K2 q = tf_enc(k, 1u, 3u);
  c0.a = p.a; c0.b = q.a;
  c1.a = p.b; c1.b = q.b;
#endif
}

// split(key, 3)
__device__ inline void split3(K2 k, K2& c0, K2& c1, K2& c2) {
#if PARTITIONABLE
  c0 = tf_enc(k, 0u, 0u);
  c1 = tf_enc(k, 0u, 1u);
  c2 = tf_enc(k, 0u, 2u);
#else
  K2 p = tf_enc(k, 0u, 3u);
  K2 q = tf_enc(k, 1u, 4u);
  K2 r = tf_enc(k, 2u, 5u);
  c0.a = p.a; c0.b = q.a;
  c1.a = r.a; c1.b = p.b;
  c2.a = q.b; c2.b = r.b;
#endif
}

// scalar random_bits(key, 32, ())
__device__ inline uint32_t draw_bits(K2 k) {
  K2 e = tf_enc(k, 0u, 0u);
#if PARTITIONABLE
  return e.a ^ e.b;
#else
  return e.a;
#endif
}

// split(key, B)[i]
__device__ inline K2 elem_key(K2 k, uint32_t i, uint32_t B) {
#if PARTITIONABLE
  return tf_enc(k, 0u, i);
#else
  if (i < (B >> 1)) {
    K2 p = tf_enc(k, 2u * i, B + 2u * i);
    K2 q = tf_enc(k, 2u * i + 1u, B + 2u * i + 1u);
    K2 r; r.a = p.a; r.b = q.a; return r;
  } else {
    uint32_t j = 2u * i - B;
    K2 p = tf_enc(k, j, 2u * i);
    K2 q = tf_enc(k, j + 1u, 2u * i + 1u);
    K2 r; r.a = p.b; r.b = q.b; return r;
  }
#endif
}

__device__ inline float u01_bits(uint32_t b) {
  return __uint_as_float((b >> 9) | 0x3F800000u) - 1.0f;
}

// XLA ErfInv32 (Giles polynomial) -- matches lax.erf_inv on f32
__device__ inline float erfinv_f32(float x) {
  float w = -log1pf(-x * x);
  float p;
  if (w < 5.0f) {
    w = w - 2.5f;
    p = 2.81022636e-08f;
    p = fmaf(p, w, 3.43273939e-07f);
    p = fmaf(p, w, -3.5233877e-06f);
    p = fmaf(p, w, -4.39150654e-06f);
    p = fmaf(p, w, 0.00021858087f);
    p = fmaf(p, w, -0.00125372503f);
    p = fmaf(p, w, -0.00417768164f);
    p = fmaf(p, w, 0.246640727f);
    p = fmaf(p, w, 1.50140941f);
  } else {
    w = sqrtf(w) - 3.0f;
    p = -0.000200214257f;
    p = fmaf(p, w, 0.000100950558f);
    p = fmaf(p, w, 0.00134934322f);
    p = fmaf(p, w, -0.00367342844f);
    p = fmaf(p, w, 0.00573950773f);
    p = fmaf(p, w, -0.0076224613f);
    p = fmaf(p, w, 0.00943887047f);
    p = fmaf(p, w, 1.00167406f);
    p = fmaf(p, w, 2.83297682f);
  }
  return p * x;
}

// jax _gamma_one with log_space=True (Marsaglia-Tsang + boost)
__device__ float log_gamma_sample(K2 key, float alpha_orig) {
  const bool boost = (alpha_orig >= 1.0f);
  const float alpha = boost ? alpha_orig : (alpha_orig + 1.0f);
  const float d = alpha - 0.33333334f;
  const float c = 0.33333334f / sqrtf(d);

  K2 k0, sub;
  split2(key, k0, sub);
  const float u_boost = u01_bits(draw_bits(sub));

  K2 kcur = k0;
  float X = 0.0f, V = 1.0f, U = 2.0f;
  while ((U >= 1.0f - 0.0331f * (X * X)) &&
         (logf(U) >= X * 0.5f + d * ((1.0f - V) + logf(V)))) {
    K2 knext, xk, Uk;
    split3(kcur, knext, xk, Uk);
    kcur = knext;
    float x, v;
    K2 ik = xk;
    do {
      K2 in0, isub;
      split2(ik, in0, isub);
      ik = in0;
      float f = u01_bits(draw_bits(isub));
      // uniform(lo=nextafter(-1,0), hi=1): (hi-lo) rounds to exactly 2.0f
      float u = fmaxf(-0.99999994f, f * 2.0f + (-0.99999994f));
      x = 1.41421356f * erfinv_f32(u);   // sqrt(2) as f32
      v = 1.0f + x * c;
    } while (v <= 0.0f);
    X = x * x;
    V = (v * v) * v;
    U = u01_bits(draw_bits(Uk));
  }
  float lg = logf(d * V);
  if (!boost) lg += log1pf(-u_boost) / alpha_orig;
  return lg;
}

// ---------------- pipeline kernels ----------------

__global__ __launch_bounds__(256) void zero_kernel(ull* p, int n) {
  int i = blockIdx.x * 256 + threadIdx.x;
  if (i < n) p[i] = 0ull;
}

// counts + fixed-point value sums per item, plus CSR-ish fill of both sides
__global__ __launch_bounds__(256) void count_fill_kernel(
    const int* __restrict__ user, const int* __restrict__ item,
    const float* __restrict__ val, int n,
    int* __restrict__ cnt, ull* __restrict__ sv,
    int* __restrict__ fu, int* __restrict__ fi,
    uint32_t* __restrict__ lu, uint32_t* __restrict__ li) {
  for (int k = blockIdx.x * 256 + threadIdx.x; k < n; k += gridDim.x * 256) {
    int it = item[k];
    atomicAdd(&cnt[it], 1);
    atomicAdd(&sv[it], (ull)llrintf(val[k] * 4294967296.0f));  // fixed-point 2^32
    int q = atomicAdd(&fi[it], 1);
    if (q < CAP_I) li[(size_t)it * CAP_I + q] = (uint32_t)k;
    int u = user[k];
    int p = atomicAdd(&fu[u], 1);
    if (p < CAP_U) lu[(size_t)u * CAP_U + p] = (uint32_t)k;
  }
}

__global__ __launch_bounds__(256) void pop_raw_kernel(const int* __restrict__ cnt,
                                                      const ull* __restrict__ sv,
                                                      float* __restrict__ pop,
                                                      double* __restrict__ nrm2) {
  __shared__ float red[4];
  int i = blockIdx.x * 256 + threadIdx.x;
  float p = 0.0f;
  if (i < NUM_I) {
    float svf = (float)((double)sv[i] * (1.0 / 4294967296.0));
    p = svf * log1pf((float)cnt[i]);
    pop[i] = p;
  }
  float sq = p * p;
  for (int o = 32; o > 0; o >>= 1) sq += __shfl_down(sq, o);
  if ((threadIdx.x & 63) == 0) red[threadIdx.x >> 6] = sq;
  __syncthreads();
  if (threadIdx.x == 0) atomicAdd(nrm2, (double)(red[0] + red[1] + red[2] + red[3]));
}

__global__ __launch_bounds__(256) void pop_norm_kernel(float* __restrict__ pop,
                                                       const double* __restrict__ nrm2,
                                                       float* __restrict__ out) {
  int i = blockIdx.x * 256 + threadIdx.x;
  if (i < NUM_I) {
    float nrm = sqrtf((float)(*nrm2));
    float v = pop[i] / (nrm + 1e-8f);
    pop[i] = v;
    out[OFF_POP + i] = v;
  }
}

__global__ __launch_bounds__(256) void act_accum_kernel(const int* __restrict__ user,
                                                        const int* __restrict__ item,
                                                        const float* __restrict__ val, int n,
                                                        const float* __restrict__ pop,
                                                        ull* __restrict__ acc) {
  for (int k = blockIdx.x * 256 + threadIdx.x; k < n; k += gridDim.x * 256) {
    float term = val[k] / log1pf(pop[item[k]] + 1e-8f);
    atomicAdd(&acc[user[k]], (ull)llrintf(term * 16777216.0f));  // fixed-point 2^24
  }
}

__global__ __launch_bounds__(256) void act_pre_kernel(const ull* __restrict__ acc,
                                                      float* __restrict__ act,
                                                      double* __restrict__ nrm2) {
  __shared__ float red[4];
  int u = blockIdx.x * 256 + threadIdx.x;
  float a = 0.0f;
  if (u < NUM_U) {
    a = (float)((double)acc[u] * (1.0 / 16777216.0));
    act[u] = a;
  }
  float sq = a * a;
  for (int o = 32; o > 0; o >>= 1) sq += __shfl_down(sq, o);
  if ((threadIdx.x & 63) == 0) red[threadIdx.x >> 6] = sq;
  __syncthreads();
  if (threadIdx.x == 0) atomicAdd(nrm2, (double)(red[0] + red[1] + red[2] + red[3]));
}

__global__ __launch_bounds__(256) void act_norm_kernel(float* __restrict__ act,
                                                       const double* __restrict__ nrm2,
                                                       float* __restrict__ out) {
  int u = blockIdx.x * 256 + threadIdx.x;
  if (u < NUM_U) {
    float nrm = sqrtf((float)(*nrm2));
    float v = act[u] / (nrm + 1e-8f);
    act[u] = v;
    out[OFF_ACT + u] = v;
  }
}

// One in-place DWT analysis level over the padded LDS buffer (8-way ILP).
// Data element i lives at buf[4+i]; front pad 4 always zero. Input data
// [0..NIN-1]; output overwrites data [0..MOUT-1]. In-place safety: batch b
// reads positions >= 4096b-4, batch b-1 writes <= 2048b-1 (disjoint for b>=1);
// within a batch, all reads precede the barrier, writes follow. Per-thread
// position order (m = tid + 256j, j ascending) identical to rounds 1-4.
template <int MOUT, bool LAST>
__device__ inline void dwt_level_inplace8(float* __restrict__ buf, int tid,
                                          float& h_acc, float& lo_acc) {
  for (int base = 0; base < MOUT; base += 2048) {
    float lov[8], hiv[8];
    int mv[8]; bool okv[8];
#pragma unroll
    for (int u = 0; u < 8; ++u) {
      int m = base + tid + (u << 8);
      bool ok = m < MOUT;
      mv[u] = m; okv[u] = ok;
      int mm = ok ? m : (MOUT - 1);
      const float* s = buf + 2 * mm + 5;   // s[-t] == data[2*mm+1-t]
      float x0 = s[0], x1 = s[-1], x2 = s[-2], x3 = s[-3], x4 = s[-4], x5 = s[-5];
      float lo = 0.0f, hi = 0.0f;
      lo += 0.035226291882100656f * x0;  hi += -0.3326705529509569f * x0;
      lo += -0.08544127388224149f * x1;  hi += 0.8068915093133388f * x1;
      lo += -0.13501102001039084f * x2;  hi += -0.4598775021193313f * x2;
      lo += 0.4598775021193313f * x3;    hi += -0.13501102001039084f * x3;
      lo += 0.8068915093133388f * x4;    hi += 0.08544127388224149f * x4;
      lo += 0.3326705529509569f * x5;    hi += 0.035226291882100656f * x5;
      lov[u] = lo; hiv[u] = hi;
    }
    if (!LAST) __syncthreads();
#pragma unroll
    for (int u = 0; u < 8; ++u) {
      if (okv[u]) {
        if (!LAST) buf[4 + mv[u]] = lov[u];
        else lo_acc += lov[u];
        h_acc += hiv[u] * hiv[u];
      }
    }
  }
}

// per-row 3-level db3 DWT stats. Level 1 is output-centric sparse: column
// bitmap + popcount rank prefix give an O(1) window-empty test per output
// position; touched positions gather <=6 taps in exact dense t-order.
// Levels 2-3 dense in-place. Bit-identical to the dense formulation.
template <int NCOLS, int M1, int M2, int M3, int CAP>
__global__ __launch_bounds__(256) void dwt_rows_kernel(
    const uint32_t* __restrict__ klist, const int* __restrict__ rowlen,
    const int* __restrict__ colsrc, const float* __restrict__ values,
    const float* __restrict__ scale_vec,
    float* __restrict__ low_out, float* __restrict__ high_out) {
  constexpr int NW = NCOLS / 32;
  static_assert(NW * 4 + NW * 2 <= 4 * CAP * 4, "bitmap+prefix must fit sort scratch");
  extern __shared__ float smem[];
  float* buf = smem;                       // M1 + 12 (data at +4)
  float* sval = buf + (M1 + 12);           // CAP sorted winner values (col asc)
  int* scol = (int*)(sval + CAP);          // CAP sorted winner cols
  // union region (4*CAP*4 bytes): phase 1-2 sort scratch, then bitmap+prefix
  float* ev = (float*)(scol + CAP);        // CAP raw scaled values
  int* ecol = (int*)(ev + CAP);            // CAP raw cols
  int* ek = ecol + CAP;                    // CAP raw original indices
  int* win = ek + CAP;                     // CAP winner flags
  uint32_t* bitmap = (uint32_t*)ev;        // NW words   (alias, phase 3+)
  uint16_t* prefix = (uint16_t*)(bitmap + NW); // NW u16 (alias, phase 3+)
  float* red = (float*)(win + CAP);        // 16
  int* s_nw = (int*)(red + 16);            // 1

  const int r = blockIdx.x;
  const int tid = threadIdx.x;
  const float scale = 1.0f + scale_vec[r];
  int n = rowlen[r];
  if (n > CAP) n = CAP;

  for (int i = tid; i < M1 + 12; i += 256) buf[i] = 0.0f;
  for (int e = tid; e < n; e += 256) {
    uint32_t k = klist[(size_t)r * CAP + e];
    ecol[e] = colsrc[k];
    ek[e] = (int)k;
    ev[e] = values[k] * scale;
  }
  if (tid == 0) *s_nw = 0;
  __syncthreads();

  // pass 1: winner flags (entry with max original index wins -- XLA scatter)
  for (int e = tid; e < n; e += 256) {
    int c = ecol[e], kk = ek[e];
    int wf = 1;
    for (int j = 0; j < n; ++j)
      if (ecol[j] == c && ek[j] > kk) { wf = 0; break; }
    win[e] = wf;
  }
  __syncthreads();
  // pass 2: rank among winners (unique cols) -> sorted scatter into scol/sval
  for (int e = tid; e < n; e += 256) {
    if (win[e]) {
      int c = ecol[e];
      int rank = 0;
      for (int j = 0; j < n; ++j)
        rank += (win[j] && (ecol[j] < c)) ? 1 : 0;
      scol[rank] = c;
      sval[rank] = ev[e];
      atomicAdd(s_nw, 1);
    }
  }
  __syncthreads();
  const int nw_cnt = *s_nw;
  // phase 3: zero bitmap (sort scratch now dead)
  for (int i = tid; i < NW; i += 256) bitmap[i] = 0u;
  __syncthreads();
  // fill bitmap from sorted cols; prefix[w] = #cols < 32w via binary search
  for (int e = tid; e < nw_cnt; e += 256)
    atomicOr(&bitmap[scol[e] >> 5], 1u << (scol[e] & 31));
  for (int w = tid; w < NW; w += 256) {
    int lo = 0, hi = nw_cnt, target = w << 5;
    while (lo < hi) {
      int mid = (lo + hi) >> 1;
      if (scol[mid] < target) lo = mid + 1; else hi = mid;
    }
    prefix[w] = (uint16_t)lo;
  }
  __syncthreads();

  // ---- sparse level 1 (output-centric) ----
  // Position m reads columns [2m-4, 2m+1] (clamped). Common case: window
  // empty -> buf stays 0 (pre-zeroed), h1 += 0 skipped (exact identity).
  // Touched: gather taps t = 2m+1-c from sval via bitmap rank, then the
  // exact 6-term dense tap sum (missing taps are exact +/-0.0).
  float h1 = 0.0f;
  for (int m = tid; m < M1; m += 256) {
    int c0 = 2 * m - 4; c0 = c0 < 0 ? 0 : c0;
    int c1 = 2 * m + 1; c1 = c1 > NCOLS - 1 ? NCOLS - 1 : c1;
    int w0 = c0 >> 5, w1 = c1 >> 5;
    uint32_t b0 = bitmap[w0];
    uint32_t mlo = ~((1u << (c0 & 31)) - 1u);
    uint32_t mhi = (uint32_t)(((uint64_t)1u << ((c1 & 31) + 1)) - 1u);
    uint32_t sel0, sel1; uint32_t b1 = 0;
    if (w1 == w0) {
      sel0 = b0 & mlo & mhi;
      sel1 = 0u;
    } else {
      b1 = bitmap[w1];
      sel0 = b0 & mlo;
      sel1 = b1 & mhi;
    }
    if (sel0 | sel1) {
      float tv0 = 0.0f, tv1 = 0.0f, tv2 = 0.0f, tv3 = 0.0f, tv4 = 0.0f, tv5 = 0.0f;
      int tp1 = 2 * m + 1;
      uint32_t s = sel0;
      while (s) {
        int b = __ffs(s) - 1; s &= s - 1u;
        int c = (w0 << 5) + b;
        int idx = (int)prefix[w0] + __popc(b0 & ((1u << b) - 1u));
        float v = sval[idx];
        int t = tp1 - c;
        if (t == 0) tv0 = v; else if (t == 1) tv1 = v; else if (t == 2) tv2 = v;
        else if (t == 3) tv3 = v; else if (t == 4) tv4 = v; else tv5 = v;
      }
      s = sel1;
      while (s) {
        int b = __ffs(s) - 1; s &= s - 1u;
        int c = (w1 << 5) + b;
        int idx = (int)prefix[w1] + __popc(b1 & ((1u << b) - 1u));
        float v = sval[idx];
        int t = tp1 - c;
        if (t == 0) tv0 = v; else if (t == 1) tv1 = v; else if (t == 2) tv2 = v;
        else if (t == 3) tv3 = v; else if (t == 4) tv4 = v; else tv5 = v;
      }
      float lo = 0.0f, hi = 0.0f;
      lo += 0.035226291882100656f * tv0;  hi += -0.3326705529509569f * tv0;
      lo += -0.08544127388224149f * tv1;  hi += 0.8068915093133388f * tv1;
      lo += -0.13501102001039084f * tv2;  hi += -0.4598775021193313f * tv2;
      lo += 0.4598775021193313f * tv3;    hi += -0.13501102001039084f * tv3;
      lo += 0.8068915093133388f * tv4;    hi += 0.08544127388224149f * tv4;
      lo += 0.3326705529509569f * tv5;    hi += 0.035226291882100656f * tv5;
      buf[4 + m] = lo;
      h1 += hi * hi;
    }
  }
  __syncthreads();

  // ---- dense levels 2-3, in place over buf ----
  float h2 = 0.0f, h3 = 0.0f, slo = 0.0f;
  float dummy = 0.0f;
  dwt_level_inplace8<M2, false>(buf, tid, h2, dummy);
  __syncthreads();
  // zero the stale gap read by level 3 (data [M2 .. M2+7])
  if (tid < 8) buf[4 + M2 + tid] = 0.0f;
  __syncthreads();
  dwt_level_inplace8<M3, true>(buf, tid, h3, slo);

  for (int o = 32; o > 0; o >>= 1) {
    h1 += __shfl_down(h1, o);
    h2 += __shfl_down(h2, o);
    h3 += __shfl_down(h3, o);
    slo += __shfl_down(slo, o);
  }
  int w = tid >> 6, lane = tid & 63;
  if (lane == 0) { red[w] = h1; red[4 + w] = h2; red[8 + w] = h3; red[12 + w] = slo; }
  __syncthreads();
  if (tid == 0) {
    float s1 = red[0] + red[1] + red[2] + red[3];
    float s2 = red[4] + red[5] + red[6] + red[7];
    float s3 = red[8] + red[9] + red[10] + red[11];
    float sl = red[12] + red[13] + red[14] + red[15];
    low_out[r] = sl / (float)M3;
    high_out[r] = sqrtf(s1) + sqrtf(s2) + sqrtf(s3);
  }
}

__global__ __launch_bounds__(256) void beta_kernel(
    const float* __restrict__ u_low, const float* __restrict__ u_high,
    const float* __restrict__ i_low, const float* __restrict__ i_high,
    float* __restrict__ out, K2 kAu, K2 kBu, K2 kAi, K2 kBi) {
  int t = blockIdx.x * 256 + threadIdx.x;
  if (t >= NUM_U + NUM_I) return;
  float low, high;
  K2 ka, kb;
  int o0, o1;
  if (t < NUM_U) {
    low = u_low[t]; high = u_high[t];
    ka = elem_key(kAu, (uint32_t)t, (uint32_t)NUM_U);
    kb = elem_key(kBu, (uint32_t)t, (uint32_t)NUM_U);
    o0 = OFF_UPW + t; o1 = OFF_UMW + t;
  } else {
    int j = t - NUM_U;
    low = i_low[j]; high = i_high[j];
    ka = elem_key(kAi, (uint32_t)j, (uint32_t)NUM_I);
    kb = elem_key(kBi, (uint32_t)j, (uint32_t)NUM_I);
    o0 = OFF_IPW + j; o1 = OFF_IMW + j;
  }
  float a1 = fmaxf(low, 1e-6f);
  float a2 = fmaxf(high, 1e-6f);
  float s = a1 + a2;
  a1 = a1 / s;
  a2 = a2 / s;
  float lga = log_gamma_sample(ka, 10.0f * a1);
  float lgb = log_gamma_sample(kb, 10.0f * a2);
  float m = fmaxf(lga, lgb);
  float na = expf(lga - m);
  float nb = expf(lgb - m);
  float w = na / (na + nb);
  out[o0] = w;
  out[o1] = 1.0f - w;
}

// ---------------- host ----------------
extern "C" void kernel_launch(void* const* d_in, const int* in_sizes, int n_in,
                              void* d_out, int out_size, void* d_ws, size_t ws_size,
                              hipStream_t stream) {
  const int* user_idx = (const int*)d_in[0];
  const int* item_idx = (const int*)d_in[1];
  const float* values = (const float*)d_in[2];
  const int NNZ = in_sizes[0];

  char* ws = (char*)d_ws;
  double* nrm2_pop = (double*)(ws + 0);
  double* nrm2_act = (double*)(ws + 8);
  ull* sv_acc = (ull*)(ws + 16);
  ull* act_acc = (ull*)(ws + 65552);
  int* cnt_i = (int*)(ws + 196624);
  float* pop = (float*)(ws + 229392);
  float* act = (float*)(ws + 262160);
  int* fill_u = (int*)(ws + 327696);
  int* fill_i = (int*)(ws + 393232);
  float* u_low = (float*)(ws + 426000);
  float* u_high = (float*)(ws + 491536);
  float* i_low = (float*)(ws + 557072);
  float* i_high = (float*)(ws + 589840);
  uint32_t* klist_u = (uint32_t*)(ws + 622608);
  uint32_t* klist_i = (uint32_t*)(ws + 11108368);
  float* out = (float*)d_out;

  // host-side key derivation: root=key(42)=(0,42); ku,ki=split(root); then
  // (key_a,key_b)=split(k) inside beta for each side.
  K2 root; root.a = 0u; root.b = 42u;
  K2 ku, ki, kAu, kBu, kAi, kBi;
  split2(root, ku, ki);
  split2(ku, kAu, kBu);
  split2(ki, kAi, kBi);

  const int zero_words = 622608 / 8;
  zero_kernel<<<(zero_words + 255) / 256, 256, 0, stream>>>((ull*)ws, zero_words);
  count_fill_kernel<<<1024, 256, 0, stream>>>(user_idx, item_idx, values, NNZ,
                                              cnt_i, sv_acc, fill_u, fill_i, klist_u, klist_i);
  pop_raw_kernel<<<NUM_I / 256, 256, 0, stream>>>(cnt_i, sv_acc, pop, nrm2_pop);
  pop_norm_kernel<<<NUM_I / 256, 256, 0, stream>>>(pop, nrm2_pop, out);
  act_accum_kernel<<<1024, 256, 0, stream>>>(user_idx, item_idx, values, NNZ, pop, act_acc);
  act_pre_kernel<<<NUM_U / 256, 256, 0, stream>>>(act_acc, act, nrm2_act);
  act_norm_kernel<<<NUM_U / 256, 256, 0, stream>>>(act, nrm2_act, out);

  // LDS layout size: buf (M1+12) + sval CAP + scol CAP + union 4*CAP + red 16 + s_nw 1
  // users: NCOLS=8192, M1=4098 -> 20348 B -> 8 blocks/CU (100% occ)
  constexpr int U_SHM = ((4098 + 12) + CAP_U + CAP_U + 4 * CAP_U + 16 + 1) * 4;
  // items: NCOLS=16384, M1=8194 -> 39036 B -> 4 blocks/CU
  constexpr int I_SHM = ((8194 + 12) + CAP_I + CAP_I + 4 * CAP_I + 16 + 1) * 4;
  hipFuncSetAttribute((const void*)dwt_rows_kernel<8192, 4098, 2051, 1028, CAP_U>,
                      hipFuncAttributeMaxDynamicSharedMemorySize, U_SHM);
  hipFuncSetAttribute((const void*)dwt_rows_kernel<16384, 8194, 4099, 2052, CAP_I>,
                      hipFuncAttributeMaxDynamicSharedMemorySize, I_SHM);

  dwt_rows_kernel<8192, 4098, 2051, 1028, CAP_U><<<NUM_U, 256, U_SHM, stream>>>(
      klist_u, fill_u, item_idx, values, act, u_low, u_high);
  dwt_rows_kernel<16384, 8194, 4099, 2052, CAP_I><<<NUM_I, 256, I_SHM, stream>>>(
      klist_i, fill_i, user_idx, values, pop, i_low, i_high);

  beta_kernel<<<(NUM_U + NUM_I + 255) / 256, 256, 0, stream>>>(
      u_low, u_high, i_low, i_high, out, kAu, kBu, kAi, kBi);
}

// Round 6
// 664.194 us; speedup vs baseline: 1.4735x; 1.3741x over previous
//
#include <hip/hip_runtime.h>
#include <stdint.h>

// ============================================================================
// PopularNicheGraphBuilder: segment-sums -> normalize -> per-row db3 DWT stats
// (in LDS) -> exact replication of jax.random.beta (threefry + Marsaglia-Tsang
// log-space gamma).
//
// Round 6: (a) O(n) dedup -- bitmap popcount-prefix rank + atomicMax winner
// (replaces two O(n^2) passes); (b) levels 2-3 sparse via touched bitmaps
// T1/T2 built with pair-OR-compress + dilate bit tricks, O(1) window-empty
// test per output, stale-cell zero-writes. All bit-identical to the dense
// formulation (skipped terms are exact +/-0.0 identities; per-thread order
// preserved). LDS unchanged: items 39.0 KB (4 blk/CU), users 19.96 KB (8).
// ============================================================================
#define PARTITIONABLE 1

typedef unsigned long long ull;

#define NUM_U 16384
#define NUM_I 8192
#define CAP_U 160
#define CAP_I 256

// output layout
#define OFF_UPW 0
#define OFF_UMW 16384
#define OFF_IPW 32768
#define OFF_IMW 40960
#define OFF_ACT 49152
#define OFF_POP 65536

// ---------------- threefry2x32 ----------------
struct K2 { uint32_t a, b; };

__host__ __device__ inline void tf2x32(uint32_t k0, uint32_t k1, uint32_t& x0, uint32_t& x1) {
  const uint32_t ks2 = k0 ^ k1 ^ 0x1BD11BDAu;
  x0 += k0; x1 += k1;
#define TF_R(r) { x0 += x1; x1 = (x1 << (r)) | (x1 >> (32 - (r))); x1 ^= x0; }
  TF_R(13) TF_R(15) TF_R(26) TF_R(6)
  x0 += k1; x1 += ks2 + 1u;
  TF_R(17) TF_R(29) TF_R(16) TF_R(24)
  x0 += ks2; x1 += k0 + 2u;
  TF_R(13) TF_R(15) TF_R(26) TF_R(6)
  x0 += k0; x1 += k1 + 3u;
  TF_R(17) TF_R(29) TF_R(16) TF_R(24)
  x0 += k1; x1 += ks2 + 4u;
  TF_R(13) TF_R(15) TF_R(26) TF_R(6)
  x0 += ks2; x1 += k0 + 5u;
#undef TF_R
}

__host__ __device__ inline K2 tf_enc(K2 k, uint32_t x0, uint32_t x1) {
  tf2x32(k.a, k.b, x0, x1);
  K2 r; r.a = x0; r.b = x1; return r;
}

// split(key) -> 2 children
__host__ __device__ inline void split2(K2 k, K2& c0, K2& c1) {
#if PARTITIONABLE
  c0 = tf_enc(k, 0u, 0u);
  c1 = tf_enc(k, 0u, 1u);
#else
  K2 p = tf_enc(k, 0u, 2u);
  K2 q = tf_enc(k, 1u, 3u);
  c0.a = p.a; c0.b = q.a;
  c1.a = p.b; c1.b = q.b;
#endif
}

// split(key, 3)
__device__ inline void split3(K2 k, K2& c0, K2& c1, K2& c2) {
#if PARTITIONABLE
  c0 = tf_enc(k, 0u, 0u);
  c1 = tf_enc(k, 0u, 1u);
  c2 = tf_enc(k, 0u, 2u);
#else
  K2 p = tf_enc(k, 0u, 3u);
  K2 q = tf_enc(k, 1u, 4u);
  K2 r = tf_enc(k, 2u, 5u);
  c0.a = p.a; c0.b = q.a;
  c1.a = r.a; c1.b = p.b;
  c2.a = q.b; c2.b = r.b;
#endif
}

// scalar random_bits(key, 32, ())
__device__ inline uint32_t draw_bits(K2 k) {
  K2 e = tf_enc(k, 0u, 0u);
#if PARTITIONABLE
  return e.a ^ e.b;
#else
  return e.a;
#endif
}

// split(key, B)[i]
__device__ inline K2 elem_key(K2 k, uint32_t i, uint32_t B) {
#if PARTITIONABLE
  return tf_enc(k, 0u, i);
#else
  if (i < (B >> 1)) {
    K2 p = tf_enc(k, 2u * i, B + 2u * i);
    K2 q = tf_enc(k, 2u * i + 1u, B + 2u * i + 1u);
    K2 r; r.a = p.a; r.b = q.a; return r;
  } else {
    uint32_t j = 2u * i - B;
    K2 p = tf_enc(k, j, 2u * i);
    K2 q = tf_enc(k, j + 1u, 2u * i + 1u);
    K2 r; r.a = p.b; r.b = q.b; return r;
  }
#endif
}

__device__ inline float u01_bits(uint32_t b) {
  return __uint_as_float((b >> 9) | 0x3F800000u) - 1.0f;
}

// XLA ErfInv32 (Giles polynomial) -- matches lax.erf_inv on f32
__device__ inline float erfinv_f32(float x) {
  float w = -log1pf(-x * x);
  float p;
  if (w < 5.0f) {
    w = w - 2.5f;
    p = 2.81022636e-08f;
    p = fmaf(p, w, 3.43273939e-07f);
    p = fmaf(p, w, -3.5233877e-06f);
    p = fmaf(p, w, -4.39150654e-06f);
    p = fmaf(p, w, 0.00021858087f);
    p = fmaf(p, w, -0.00125372503f);
    p = fmaf(p, w, -0.00417768164f);
    p = fmaf(p, w, 0.246640727f);
    p = fmaf(p, w, 1.50140941f);
  } else {
    w = sqrtf(w) - 3.0f;
    p = -0.000200214257f;
    p = fmaf(p, w, 0.000100950558f);
    p = fmaf(p, w, 0.00134934322f);
    p = fmaf(p, w, -0.00367342844f);
    p = fmaf(p, w, 0.00573950773f);
    p = fmaf(p, w, -0.0076224613f);
    p = fmaf(p, w, 0.00943887047f);
    p = fmaf(p, w, 1.00167406f);
    p = fmaf(p, w, 2.83297682f);
  }
  return p * x;
}

// jax _gamma_one with log_space=True (Marsaglia-Tsang + boost)
__device__ float log_gamma_sample(K2 key, float alpha_orig) {
  const bool boost = (alpha_orig >= 1.0f);
  const float alpha = boost ? alpha_orig : (alpha_orig + 1.0f);
  const float d = alpha - 0.33333334f;
  const float c = 0.33333334f / sqrtf(d);

  K2 k0, sub;
  split2(key, k0, sub);
  const float u_boost = u01_bits(draw_bits(sub));

  K2 kcur = k0;
  float X = 0.0f, V = 1.0f, U = 2.0f;
  while ((U >= 1.0f - 0.0331f * (X * X)) &&
         (logf(U) >= X * 0.5f + d * ((1.0f - V) + logf(V)))) {
    K2 knext, xk, Uk;
    split3(kcur, knext, xk, Uk);
    kcur = knext;
    float x, v;
    K2 ik = xk;
    do {
      K2 in0, isub;
      split2(ik, in0, isub);
      ik = in0;
      float f = u01_bits(draw_bits(isub));
      // uniform(lo=nextafter(-1,0), hi=1): (hi-lo) rounds to exactly 2.0f
      float u = fmaxf(-0.99999994f, f * 2.0f + (-0.99999994f));
      x = 1.41421356f * erfinv_f32(u);   // sqrt(2) as f32
      v = 1.0f + x * c;
    } while (v <= 0.0f);
    X = x * x;
    V = (v * v) * v;
    U = u01_bits(draw_bits(Uk));
  }
  float lg = logf(d * V);
  if (!boost) lg += log1pf(-u_boost) / alpha_orig;
  return lg;
}

// ---------------- pipeline kernels ----------------

__global__ __launch_bounds__(256) void zero_kernel(ull* p, int n) {
  int i = blockIdx.x * 256 + threadIdx.x;
  if (i < n) p[i] = 0ull;
}

// counts + fixed-point value sums per item, plus CSR-ish fill of both sides
__global__ __launch_bounds__(256) void count_fill_kernel(
    const int* __restrict__ user, const int* __restrict__ item,
    const float* __restrict__ val, int n,
    int* __restrict__ cnt, ull* __restrict__ sv,
    int* __restrict__ fu, int* __restrict__ fi,
    uint32_t* __restrict__ lu, uint32_t* __restrict__ li) {
  for (int k = blockIdx.x * 256 + threadIdx.x; k < n; k += gridDim.x * 256) {
    int it = item[k];
    atomicAdd(&cnt[it], 1);
    atomicAdd(&sv[it], (ull)llrintf(val[k] * 4294967296.0f));  // fixed-point 2^32
    int q = atomicAdd(&fi[it], 1);
    if (q < CAP_I) li[(size_t)it * CAP_I + q] = (uint32_t)k;
    int u = user[k];
    int p = atomicAdd(&fu[u], 1);
    if (p < CAP_U) lu[(size_t)u * CAP_U + p] = (uint32_t)k;
  }
}

__global__ __launch_bounds__(256) void pop_raw_kernel(const int* __restrict__ cnt,
                                                      const ull* __restrict__ sv,
                                                      float* __restrict__ pop,
                                                      double* __restrict__ nrm2) {
  __shared__ float red[4];
  int i = blockIdx.x * 256 + threadIdx.x;
  float p = 0.0f;
  if (i < NUM_I) {
    float svf = (float)((double)sv[i] * (1.0 / 4294967296.0));
    p = svf * log1pf((float)cnt[i]);
    pop[i] = p;
  }
  float sq = p * p;
  for (int o = 32; o > 0; o >>= 1) sq += __shfl_down(sq, o);
  if ((threadIdx.x & 63) == 0) red[threadIdx.x >> 6] = sq;
  __syncthreads();
  if (threadIdx.x == 0) atomicAdd(nrm2, (double)(red[0] + red[1] + red[2] + red[3]));
}

__global__ __launch_bounds__(256) void pop_norm_kernel(float* __restrict__ pop,
                                                       const double* __restrict__ nrm2,
                                                       float* __restrict__ out) {
  int i = blockIdx.x * 256 + threadIdx.x;
  if (i < NUM_I) {
    float nrm = sqrtf((float)(*nrm2));
    float v = pop[i] / (nrm + 1e-8f);
    pop[i] = v;
    out[OFF_POP + i] = v;
  }
}

__global__ __launch_bounds__(256) void act_accum_kernel(const int* __restrict__ user,
                                                        const int* __restrict__ item,
                                                        const float* __restrict__ val, int n,
                                                        const float* __restrict__ pop,
                                                        ull* __restrict__ acc) {
  for (int k = blockIdx.x * 256 + threadIdx.x; k < n; k += gridDim.x * 256) {
    float term = val[k] / log1pf(pop[item[k]] + 1e-8f);
    atomicAdd(&acc[user[k]], (ull)llrintf(term * 16777216.0f));  // fixed-point 2^24
  }
}

__global__ __launch_bounds__(256) void act_pre_kernel(const ull* __restrict__ acc,
                                                      float* __restrict__ act,
                                                      double* __restrict__ nrm2) {
  __shared__ float red[4];
  int u = blockIdx.x * 256 + threadIdx.x;
  float a = 0.0f;
  if (u < NUM_U) {
    a = (float)((double)acc[u] * (1.0 / 16777216.0));
    act[u] = a;
  }
  float sq = a * a;
  for (int o = 32; o > 0; o >>= 1) sq += __shfl_down(sq, o);
  if ((threadIdx.x & 63) == 0) red[threadIdx.x >> 6] = sq;
  __syncthreads();
  if (threadIdx.x == 0) atomicAdd(nrm2, (double)(red[0] + red[1] + red[2] + red[3]));
}

__global__ __launch_bounds__(256) void act_norm_kernel(float* __restrict__ act,
                                                       const double* __restrict__ nrm2,
                                                       float* __restrict__ out) {
  int u = blockIdx.x * 256 + threadIdx.x;
  if (u < NUM_U) {
    float nrm = sqrtf((float)(*nrm2));
    float v = act[u] / (nrm + 1e-8f);
    act[u] = v;
    out[OFF_ACT + u] = v;
  }
}

// ---------------- bit tricks for touched-output bitmaps ----------------
// evencomp: pair-OR bits (2i,2i+1) -> bit i (low 16 of result)
__device__ inline uint32_t evencomp(uint32_t x) {
  x = (x | (x >> 1)) & 0x55555555u;
  x = (x | (x >> 1)) & 0x33333333u;
  x = (x | (x >> 2)) & 0x0F0F0F0Fu;
  x = (x | (x >> 4)) & 0x00FF00FFu;
  x = (x | (x >> 8)) & 0x0000FFFFu;
  return x;
}
// H word i over input bitmap B: H[32i+j] = B[64i+2j] | B[64i+2j+1]
template <int NWIN>
__device__ inline uint32_t hword(const uint32_t* B, int i) {
  uint32_t a = (2 * i < NWIN) ? B[2 * i] : 0u;
  uint32_t b = (2 * i + 1 < NWIN) ? B[2 * i + 1] : 0u;
  return evencomp(a) | (evencomp(b) << 16);
}
// touched-output word w: T[m] = H[m] | H[m-1] | H[m-2]
// (output m reads input cols [2m-4, 2m+1] = pairs m-2, m-1, m)
template <int NWIN>
__device__ inline uint32_t tword(const uint32_t* B, int w) {
  uint32_t h = hword<NWIN>(B, w);
  uint32_t hp = (w > 0) ? hword<NWIN>(B, w - 1) : 0u;
  return h | (h << 1) | (h << 2) | (hp >> 31) | (hp >> 30);
}

// One sparse in-place DWT level (levels 2-3). tin = touched bitmap over the
// NIN input positions (superset of nonzeros; untouched cells are exact +0.0).
// Batched read->barrier->write preserves the in-place safety proof (batch b
// reads >= 4096b-4, writes < 2048(b+1)) and the per-thread position order
// (m = tid + 256j, j ascending) of the dense versions. Skipped compute terms
// are exact +/-0.0 identities -> bit-identical results. Stale cells (input
// bit set at output index, window empty) get an explicit 0.0f write.
template <int MOUT, int NIN, bool LAST>
__device__ inline void dwt_level_sparse(float* __restrict__ buf,
                                        const uint32_t* __restrict__ tin,
                                        int tid, float& h_acc, float& lo_acc) {
  for (int base = 0; base < MOUT; base += 2048) {
    float lov[8], hiv[8];
    int mv[8];
    bool comp[8], stale[8];
#pragma unroll
    for (int u = 0; u < 8; ++u) {
      int m = base + tid + (u << 8);
      bool ok = m < MOUT;
      mv[u] = m;
      int mm = ok ? m : (MOUT - 1);
      int c0 = 2 * mm - 4; c0 = c0 < 0 ? 0 : c0;
      int c1 = 2 * mm + 1; c1 = c1 > NIN - 1 ? NIN - 1 : c1;
      int w0 = c0 >> 5, w1 = c1 >> 5;
      uint32_t b0 = tin[w0];
      uint32_t mlo = ~((1u << (c0 & 31)) - 1u);
      uint32_t mhi = (uint32_t)(((uint64_t)1u << ((c1 & 31) + 1)) - 1u);
      uint32_t sel = (w1 == w0) ? (b0 & mlo & mhi) : ((b0 & mlo) | (tin[w1] & mhi));
      bool touched = ok && (sel != 0u);
      comp[u] = touched;
      stale[u] = (!LAST) && ok && (((tin[mm >> 5] >> (mm & 31)) & 1u) != 0u);
      lov[u] = 0.0f; hiv[u] = 0.0f;
      if (touched) {
        const float* s = buf + 2 * mm + 5;   // s[-t] == data[2*mm+1-t]
        float x0 = s[0], x1 = s[-1], x2 = s[-2], x3 = s[-3], x4 = s[-4], x5 = s[-5];
        float lo = 0.0f, hi = 0.0f;
        lo += 0.035226291882100656f * x0;  hi += -0.3326705529509569f * x0;
        lo += -0.08544127388224149f * x1;  hi += 0.8068915093133388f * x1;
        lo += -0.13501102001039084f * x2;  hi += -0.4598775021193313f * x2;
        lo += 0.4598775021193313f * x3;    hi += -0.13501102001039084f * x3;
        lo += 0.8068915093133388f * x4;    hi += 0.08544127388224149f * x4;
        lo += 0.3326705529509569f * x5;    hi += 0.035226291882100656f * x5;
        lov[u] = lo; hiv[u] = hi;
      }
    }
    if (!LAST) __syncthreads();
#pragma unroll
    for (int u = 0; u < 8; ++u) {
      if (comp[u]) {
        if (!LAST) buf[4 + mv[u]] = lov[u];
        else lo_acc += lov[u];
        h_acc += hiv[u] * hiv[u];
      } else if (stale[u]) {
        buf[4 + mv[u]] = 0.0f;   // clear stale input so next level reads +0.0
      }
    }
  }
}

// per-row 3-level db3 DWT stats. Dedup O(n) via bitmap-rank + atomicMax;
// level 1 output-centric sparse with rank gather; levels 2-3 sparse via
// touched bitmaps T1/T2 (aliased over dead staging arrays).
template <int NCOLS, int M1, int M2, int M3, int CAP>
__global__ __launch_bounds__(256) void dwt_rows_kernel(
    const uint32_t* __restrict__ klist, const int* __restrict__ rowlen,
    const int* __restrict__ colsrc, const float* __restrict__ values,
    const float* __restrict__ scale_vec,
    float* __restrict__ low_out, float* __restrict__ high_out) {
  constexpr int NW = NCOLS / 32;        // col bitmap words
  constexpr int WPT = NW / 256;         // words per thread in the scan
  constexpr int NW1 = (M1 + 31) / 32;   // T1 words
  constexpr int NW2 = (M2 + 31) / 32;   // T2 words
  static_assert(NW1 + NW2 <= 2 * CAP, "T1+T2 must fit ecol+ek");
  static_assert(WPT * 256 == NW, "NW must be a multiple of 256");
  extern __shared__ float smem[];
  float* buf = smem;                          // M1+12 (data at +4)
  int* slot = (int*)(buf + (M1 + 12));        // CAP winner codes; sval aliases
  float* sval = (float*)slot;                 // CAP winner values (rank order)
  uint32_t* treg = (uint32_t*)(slot + CAP);   // 2*CAP: ecol+ek, then T1+T2
  int* ecol = (int*)treg;                     // CAP staged cols
  int* ek = ecol + CAP;                       // CAP staged orig indices
  uint32_t* T1 = treg;                        // NW1 (alias, after dedup)
  uint32_t* T2 = treg + NW1;                  // NW2
  uint32_t* bitmap = (uint32_t*)(ek + CAP);   // NW
  uint16_t* prefix = (uint16_t*)(bitmap + NW);// NW u16
  float* red = (float*)(prefix + NW);         // 16
  int* s_nw = (int*)(red + 16);               // 1

  const int r = blockIdx.x;
  const int tid = threadIdx.x;
  const float scale = 1.0f + scale_vec[r];
  int n = rowlen[r];
  if (n > CAP) n = CAP;

  // init
  for (int i = tid; i < M1 + 12; i += 256) buf[i] = 0.0f;
  for (int i = tid; i < NW; i += 256) bitmap[i] = 0u;
  for (int i = tid; i < CAP; i += 256) slot[i] = 0;
  __syncthreads();

  // stage entries + column bitmap
  for (int e = tid; e < n; e += 256) {
    uint32_t k = klist[(size_t)r * CAP + e];
    int c = colsrc[k];
    ecol[e] = c;
    ek[e] = (int)k;
    atomicOr(&bitmap[c >> 5], 1u << (c & 31));
  }
  __syncthreads();

  // popcount prefix scan over bitmap words -> prefix[w] = #distinct cols < 32w
  {
    int v = 0;
#pragma unroll
    for (int j = 0; j < WPT; ++j) v += __popc(bitmap[tid * WPT + j]);
    int lane = tid & 63, wid = tid >> 6;
    int incl = v;
    for (int off = 1; off < 64; off <<= 1) {
      int y = __shfl_up(incl, off, 64);
      if (lane >= off) incl += y;
    }
    int* isc = (int*)red;
    if (lane == 63) isc[wid] = incl;
    __syncthreads();
    int base = 0;
    for (int ww = 0; ww < wid; ++ww) base += isc[ww];
    int run = base + incl - v;
#pragma unroll
    for (int j = 0; j < WPT; ++j) {
      prefix[tid * WPT + j] = (uint16_t)run;
      run += __popc(bitmap[tid * WPT + j]);
    }
    if (tid == 255) *s_nw = run;   // total distinct cols
  }
  __syncthreads();

  // O(n) dedup: rank(col) via bitmap+prefix, winner = max orig index k
  for (int e = tid; e < n; e += 256) {
    int c = ecol[e];
    int w = c >> 5;
    int rank = (int)prefix[w] + __popc(bitmap[w] & ((1u << (c & 31)) - 1u));
    atomicMax(&slot[rank], ek[e] + 1);
  }
  __syncthreads();
  const int nw_cnt = *s_nw;

  // compact winner values (slot -> sval in place) + build T1 (ecol/ek dead)
  for (int rr = tid; rr < nw_cnt; rr += 256) {
    int k = slot[rr] - 1;
    sval[rr] = values[k] * scale;
  }
  for (int w = tid; w < NW1; w += 256) T1[w] = tword<NW>(bitmap, w);
  __syncthreads();

  // ---- level 1: output-centric sparse with rank gather ----
  float h1 = 0.0f;
  for (int m = tid; m < M1; m += 256) {
    int c0 = 2 * m - 4; c0 = c0 < 0 ? 0 : c0;
    int c1 = 2 * m + 1; c1 = c1 > NCOLS - 1 ? NCOLS - 1 : c1;
    int w0 = c0 >> 5, w1 = c1 >> 5;
    uint32_t b0 = bitmap[w0];
    uint32_t mlo = ~((1u << (c0 & 31)) - 1u);
    uint32_t mhi = (uint32_t)(((uint64_t)1u << ((c1 & 31) + 1)) - 1u);
    uint32_t sel0, sel1; uint32_t b1 = 0;
    if (w1 == w0) {
      sel0 = b0 & mlo & mhi;
      sel1 = 0u;
    } else {
      b1 = bitmap[w1];
      sel0 = b0 & mlo;
      sel1 = b1 & mhi;
    }
    if (sel0 | sel1) {
      float tv0 = 0.0f, tv1 = 0.0f, tv2 = 0.0f, tv3 = 0.0f, tv4 = 0.0f, tv5 = 0.0f;
      int tp1 = 2 * m + 1;
      uint32_t s = sel0;
      while (s) {
        int b = __ffs(s) - 1; s &= s - 1u;
        int c = (w0 << 5) + b;
        int idx = (int)prefix[w0] + __popc(b0 & ((1u << b) - 1u));
        float v = sval[idx];
        int t = tp1 - c;
        if (t == 0) tv0 = v; else if (t == 1) tv1 = v; else if (t == 2) tv2 = v;
        else if (t == 3) tv3 = v; else if (t == 4) tv4 = v; else tv5 = v;
      }
      s = sel1;
      while (s) {
        int b = __ffs(s) - 1; s &= s - 1u;
        int c = (w1 << 5) + b;
        int idx = (int)prefix[w1] + __popc(b1 & ((1u << b) - 1u));
        float v = sval[idx];
        int t = tp1 - c;
        if (t == 0) tv0 = v; else if (t == 1) tv1 = v; else if (t == 2) tv2 = v;
        else if (t == 3) tv3 = v; else if (t == 4) tv4 = v; else tv5 = v;
      }
      float lo = 0.0f, hi = 0.0f;
      lo += 0.035226291882100656f * tv0;  hi += -0.3326705529509569f * tv0;
      lo += -0.08544127388224149f * tv1;  hi += 0.8068915093133388f * tv1;
      lo += -0.13501102001039084f * tv2;  hi += -0.4598775021193313f * tv2;
      lo += 0.4598775021193313f * tv3;    hi += -0.13501102001039084f * tv3;
      lo += 0.8068915093133388f * tv4;    hi += 0.08544127388224149f * tv4;
      lo += 0.3326705529509569f * tv5;    hi += 0.035226291882100656f * tv5;
      buf[4 + m] = lo;
      h1 += hi * hi;
    }
  }
  // build T2 from T1 (T1 complete as of the last barrier)
  for (int w = tid; w < NW2; w += 256) T2[w] = tword<NW1>(T1, w);
  __syncthreads();

  // ---- sparse levels 2-3, in place over buf ----
  float h2 = 0.0f, h3 = 0.0f, slo = 0.0f;
  float dummy = 0.0f;
  dwt_level_sparse<M2, M1, false>(buf, T1, tid, h2, dummy);
  __syncthreads();
  // zero the stale gap read by level 3 (data [M2 .. M2+7])
  if (tid < 8) buf[4 + M2 + tid] = 0.0f;
  __syncthreads();
  dwt_level_sparse<M3, M2, true>(buf, T2, tid, h3, slo);

  for (int o = 32; o > 0; o >>= 1) {
    h1 += __shfl_down(h1, o);
    h2 += __shfl_down(h2, o);
    h3 += __shfl_down(h3, o);
    slo += __shfl_down(slo, o);
  }
  int w = tid >> 6, lane = tid & 63;
  if (lane == 0) { red[w] = h1; red[4 + w] = h2; red[8 + w] = h3; red[12 + w] = slo; }
  __syncthreads();
  if (tid == 0) {
    float s1 = red[0] + red[1] + red[2] + red[3];
    float s2 = red[4] + red[5] + red[6] + red[7];
    float s3 = red[8] + red[9] + red[10] + red[11];
    float sl = red[12] + red[13] + red[14] + red[15];
    low_out[r] = sl / (float)M3;
    high_out[r] = sqrtf(s1) + sqrtf(s2) + sqrtf(s3);
  }
}

__global__ __launch_bounds__(256) void beta_kernel(
    const float* __restrict__ u_low, const float* __restrict__ u_high,
    const float* __restrict__ i_low, const float* __restrict__ i_high,
    float* __restrict__ out, K2 kAu, K2 kBu, K2 kAi, K2 kBi) {
  int t = blockIdx.x * 256 + threadIdx.x;
  if (t >= NUM_U + NUM_I) return;
  float low, high;
  K2 ka, kb;
  int o0, o1;
  if (t < NUM_U) {
    low = u_low[t]; high = u_high[t];
    ka = elem_key(kAu, (uint32_t)t, (uint32_t)NUM_U);
    kb = elem_key(kBu, (uint32_t)t, (uint32_t)NUM_U);
    o0 = OFF_UPW + t; o1 = OFF_UMW + t;
  } else {
    int j = t - NUM_U;
    low = i_low[j]; high = i_high[j];
    ka = elem_key(kAi, (uint32_t)j, (uint32_t)NUM_I);
    kb = elem_key(kBi, (uint32_t)j, (uint32_t)NUM_I);
    o0 = OFF_IPW + j; o1 = OFF_IMW + j;
  }
  float a1 = fmaxf(low, 1e-6f);
  float a2 = fmaxf(high, 1e-6f);
  float s = a1 + a2;
  a1 = a1 / s;
  a2 = a2 / s;
  float lga = log_gamma_sample(ka, 10.0f * a1);
  float lgb = log_gamma_sample(kb, 10.0f * a2);
  float m = fmaxf(lga, lgb);
  float na = expf(lga - m);
  float nb = expf(lgb - m);
  float w = na / (na + nb);
  out[o0] = w;
  out[o1] = 1.0f - w;
}

// ---------------- host ----------------
extern "C" void kernel_launch(void* const* d_in, const int* in_sizes, int n_in,
                              void* d_out, int out_size, void* d_ws, size_t ws_size,
                              hipStream_t stream) {
  const int* user_idx = (const int*)d_in[0];
  const int* item_idx = (const int*)d_in[1];
  const float* values = (const float*)d_in[2];
  const int NNZ = in_sizes[0];

  char* ws = (char*)d_ws;
  double* nrm2_pop = (double*)(ws + 0);
  double* nrm2_act = (double*)(ws + 8);
  ull* sv_acc = (ull*)(ws + 16);
  ull* act_acc = (ull*)(ws + 65552);
  int* cnt_i = (int*)(ws + 196624);
  float* pop = (float*)(ws + 229392);
  float* act = (float*)(ws + 262160);
  int* fill_u = (int*)(ws + 327696);
  int* fill_i = (int*)(ws + 393232);
  float* u_low = (float*)(ws + 426000);
  float* u_high = (float*)(ws + 491536);
  float* i_low = (float*)(ws + 557072);
  float* i_high = (float*)(ws + 589840);
  uint32_t* klist_u = (uint32_t*)(ws + 622608);
  uint32_t* klist_i = (uint32_t*)(ws + 11108368);
  float* out = (float*)d_out;

  // host-side key derivation: root=key(42)=(0,42); ku,ki=split(root); then
  // (key_a,key_b)=split(k) inside beta for each side.
  K2 root; root.a = 0u; root.b = 42u;
  K2 ku, ki, kAu, kBu, kAi, kBi;
  split2(root, ku, ki);
  split2(ku, kAu, kBu);
  split2(ki, kAi, kBi);

  const int zero_words = 622608 / 8;
  zero_kernel<<<(zero_words + 255) / 256, 256, 0, stream>>>((ull*)ws, zero_words);
  count_fill_kernel<<<1024, 256, 0, stream>>>(user_idx, item_idx, values, NNZ,
                                              cnt_i, sv_acc, fill_u, fill_i, klist_u, klist_i);
  pop_raw_kernel<<<NUM_I / 256, 256, 0, stream>>>(cnt_i, sv_acc, pop, nrm2_pop);
  pop_norm_kernel<<<NUM_I / 256, 256, 0, stream>>>(pop, nrm2_pop, out);
  act_accum_kernel<<<1024, 256, 0, stream>>>(user_idx, item_idx, values, NNZ, pop, act_acc);
  act_pre_kernel<<<NUM_U / 256, 256, 0, stream>>>(act_acc, act, nrm2_act);
  act_norm_kernel<<<NUM_U / 256, 256, 0, stream>>>(act, nrm2_act, out);

  // LDS words: buf(M1+12) + slot CAP + ecol/ek 2*CAP + bitmap NW + prefix NW/2 + red 16 + 1
  // users: 4110+160+320+256+128+16+1 = 4991 w = 19964 B -> 8 blocks/CU
  constexpr int U_SHM = ((4098 + 12) + 3 * CAP_U + 256 + 128 + 16 + 1) * 4;
  // items: 8206+256+512+512+256+16+1 = 9759 w = 39036 B -> 4 blocks/CU
  constexpr int I_SHM = ((8194 + 12) + 3 * CAP_I + 512 + 256 + 16 + 1) * 4;
  hipFuncSetAttribute((const void*)dwt_rows_kernel<8192, 4098, 2051, 1028, CAP_U>,
                      hipFuncAttributeMaxDynamicSharedMemorySize, U_SHM);
  hipFuncSetAttribute((const void*)dwt_rows_kernel<16384, 8194, 4099, 2052, CAP_I>,
                      hipFuncAttributeMaxDynamicSharedMemorySize, I_SHM);

  dwt_rows_kernel<8192, 4098, 2051, 1028, CAP_U><<<NUM_U, 256, U_SHM, stream>>>(
      klist_u, fill_u, item_idx, values, act, u_low, u_high);
  dwt_rows_kernel<16384, 8194, 4099, 2052, CAP_I><<<NUM_I, 256, I_SHM, stream>>>(
      klist_i, fill_i, user_idx, values, pop, i_low, i_high);

  beta_kernel<<<(NUM_U + NUM_I + 255) / 256, 256, 0, stream>>>(
      u_low, u_high, i_low, i_high, out, kAu, kBu, kAi, kBi);
}

// Round 7
// 596.996 us; speedup vs baseline: 1.6394x; 1.1126x over previous
//
#include <hip/hip_runtime.h>
#include <stdint.h>

// ============================================================================
// PopularNicheGraphBuilder: segment-sums -> normalize -> per-row db3 DWT stats
// (in LDS) -> exact replication of jax.random.beta (threefry + Marsaglia-Tsang
// log-space gamma).
//
// Round 7: O(1) touched tests -- per-level touched-output bitmaps T1/T2/T3
// (T3 = tword(T2) added) replace the per-position window-mask computation;
// bit = tid&31 is a per-thread constant, so each test is one LDS word read +
// AND. Condition equivalence is exact (T bit == OR of window bits), so all
// arithmetic, ownership, and order are unchanged -> bit-identical outputs.
// Plus: float4 LDS zeroing; count_fill drops the cnt atomic (fi is the count).
// ============================================================================
#define PARTITIONABLE 1

typedef unsigned long long ull;

#define NUM_U 16384
#define NUM_I 8192
#define CAP_U 160
#define CAP_I 256

// output layout
#define OFF_UPW 0
#define OFF_UMW 16384
#define OFF_IPW 32768
#define OFF_IMW 40960
#define OFF_ACT 49152
#define OFF_POP 65536

// ---------------- threefry2x32 ----------------
struct K2 { uint32_t a, b; };

__host__ __device__ inline void tf2x32(uint32_t k0, uint32_t k1, uint32_t& x0, uint32_t& x1) {
  const uint32_t ks2 = k0 ^ k1 ^ 0x1BD11BDAu;
  x0 += k0; x1 += k1;
#define TF_R(r) { x0 += x1; x1 = (x1 << (r)) | (x1 >> (32 - (r))); x1 ^= x0; }
  TF_R(13) TF_R(15) TF_R(26) TF_R(6)
  x0 += k1; x1 += ks2 + 1u;
  TF_R(17) TF_R(29) TF_R(16) TF_R(24)
  x0 += ks2; x1 += k0 + 2u;
  TF_R(13) TF_R(15) TF_R(26) TF_R(6)
  x0 += k0; x1 += k1 + 3u;
  TF_R(17) TF_R(29) TF_R(16) TF_R(24)
  x0 += k1; x1 += ks2 + 4u;
  TF_R(13) TF_R(15) TF_R(26) TF_R(6)
  x0 += ks2; x1 += k0 + 5u;
#undef TF_R
}

__host__ __device__ inline K2 tf_enc(K2 k, uint32_t x0, uint32_t x1) {
  tf2x32(k.a, k.b, x0, x1);
  K2 r; r.a = x0; r.b = x1; return r;
}

// split(key) -> 2 children
__host__ __device__ inline void split2(K2 k, K2& c0, K2& c1) {
#if PARTITIONABLE
  c0 = tf_enc(k, 0u, 0u);
  c1 = tf_enc(k, 0u, 1u);
#else
  K2 p = tf_enc(k, 0u, 2u);
  K2 q = tf_enc(k, 1u, 3u);
  c0.a = p.a; c0.b = q.a;
  c1.a = p.b; c1.b = q.b;
#endif
}

// split(key, 3)
__device__ inline void split3(K2 k, K2& c0, K2& c1, K2& c2) {
#if PARTITIONABLE
  c0 = tf_enc(k, 0u, 0u);
  c1 = tf_enc(k, 0u, 1u);
  c2 = tf_enc(k, 0u, 2u);
#else
  K2 p = tf_enc(k, 0u, 3u);
  K2 q = tf_enc(k, 1u, 4u);
  K2 r = tf_enc(k, 2u, 5u);
  c0.a = p.a; c0.b = q.a;
  c1.a = r.a; c1.b = p.b;
  c2.a = q.b; c2.b = r.b;
#endif
}

// scalar random_bits(key, 32, ())
__device__ inline uint32_t draw_bits(K2 k) {
  K2 e = tf_enc(k, 0u, 0u);
#if PARTITIONABLE
  return e.a ^ e.b;
#else
  return e.a;
#endif
}

// split(key, B)[i]
__device__ inline K2 elem_key(K2 k, uint32_t i, uint32_t B) {
#if PARTITIONABLE
  return tf_enc(k, 0u, i);
#else
  if (i < (B >> 1)) {
    K2 p = tf_enc(k, 2u * i, B + 2u * i);
    K2 q = tf_enc(k, 2u * i + 1u, B + 2u * i + 1u);
    K2 r; r.a = p.a; r.b = q.a; return r;
  } else {
    uint32_t j = 2u * i - B;
    K2 p = tf_enc(k, j, 2u * i);
    K2 q = tf_enc(k, j + 1u, 2u * i + 1u);
    K2 r; r.a = p.b; r.b = q.b; return r;
  }
#endif
}

__device__ inline float u01_bits(uint32_t b) {
  return __uint_as_float((b >> 9) | 0x3F800000u) - 1.0f;
}

// XLA ErfInv32 (Giles polynomial) -- matches lax.erf_inv on f32
__device__ inline float erfinv_f32(float x) {
  float w = -log1pf(-x * x);
  float p;
  if (w < 5.0f) {
    w = w - 2.5f;
    p = 2.81022636e-08f;
    p = fmaf(p, w, 3.43273939e-07f);
    p = fmaf(p, w, -3.5233877e-06f);
    p = fmaf(p, w, -4.39150654e-06f);
    p = fmaf(p, w, 0.00021858087f);
    p = fmaf(p, w, -0.00125372503f);
    p = fmaf(p, w, -0.00417768164f);
    p = fmaf(p, w, 0.246640727f);
    p = fmaf(p, w, 1.50140941f);
  } else {
    w = sqrtf(w) - 3.0f;
    p = -0.000200214257f;
    p = fmaf(p, w, 0.000100950558f);
    p = fmaf(p, w, 0.00134934322f);
    p = fmaf(p, w, -0.00367342844f);
    p = fmaf(p, w, 0.00573950773f);
    p = fmaf(p, w, -0.0076224613f);
    p = fmaf(p, w, 0.00943887047f);
    p = fmaf(p, w, 1.00167406f);
    p = fmaf(p, w, 2.83297682f);
  }
  return p * x;
}

// jax _gamma_one with log_space=True (Marsaglia-Tsang + boost)
__device__ float log_gamma_sample(K2 key, float alpha_orig) {
  const bool boost = (alpha_orig >= 1.0f);
  const float alpha = boost ? alpha_orig : (alpha_orig + 1.0f);
  const float d = alpha - 0.33333334f;
  const float c = 0.33333334f / sqrtf(d);

  K2 k0, sub;
  split2(key, k0, sub);
  const float u_boost = u01_bits(draw_bits(sub));

  K2 kcur = k0;
  float X = 0.0f, V = 1.0f, U = 2.0f;
  while ((U >= 1.0f - 0.0331f * (X * X)) &&
         (logf(U) >= X * 0.5f + d * ((1.0f - V) + logf(V)))) {
    K2 knext, xk, Uk;
    split3(kcur, knext, xk, Uk);
    kcur = knext;
    float x, v;
    K2 ik = xk;
    do {
      K2 in0, isub;
      split2(ik, in0, isub);
      ik = in0;
      float f = u01_bits(draw_bits(isub));
      // uniform(lo=nextafter(-1,0), hi=1): (hi-lo) rounds to exactly 2.0f
      float u = fmaxf(-0.99999994f, f * 2.0f + (-0.99999994f));
      x = 1.41421356f * erfinv_f32(u);   // sqrt(2) as f32
      v = 1.0f + x * c;
    } while (v <= 0.0f);
    X = x * x;
    V = (v * v) * v;
    U = u01_bits(draw_bits(Uk));
  }
  float lg = logf(d * V);
  if (!boost) lg += log1pf(-u_boost) / alpha_orig;
  return lg;
}

// ---------------- pipeline kernels ----------------

__global__ __launch_bounds__(256) void zero_kernel(ull* p, int n) {
  int i = blockIdx.x * 256 + threadIdx.x;
  if (i < n) p[i] = 0ull;
}

// fixed-point value sums per item + CSR-ish fill of both sides (fi/fu double
// as the per-item / per-user counts)
__global__ __launch_bounds__(256) void count_fill_kernel(
    const int* __restrict__ user, const int* __restrict__ item,
    const float* __restrict__ val, int n,
    ull* __restrict__ sv,
    int* __restrict__ fu, int* __restrict__ fi,
    uint32_t* __restrict__ lu, uint32_t* __restrict__ li) {
  for (int k = blockIdx.x * 256 + threadIdx.x; k < n; k += gridDim.x * 256) {
    int it = item[k];
    atomicAdd(&sv[it], (ull)llrintf(val[k] * 4294967296.0f));  // fixed-point 2^32
    int q = atomicAdd(&fi[it], 1);
    if (q < CAP_I) li[(size_t)it * CAP_I + q] = (uint32_t)k;
    int u = user[k];
    int p = atomicAdd(&fu[u], 1);
    if (p < CAP_U) lu[(size_t)u * CAP_U + p] = (uint32_t)k;
  }
}

__global__ __launch_bounds__(256) void pop_raw_kernel(const int* __restrict__ cnt,
                                                      const ull* __restrict__ sv,
                                                      float* __restrict__ pop,
                                                      double* __restrict__ nrm2) {
  __shared__ float red[4];
  int i = blockIdx.x * 256 + threadIdx.x;
  float p = 0.0f;
  if (i < NUM_I) {
    float svf = (float)((double)sv[i] * (1.0 / 4294967296.0));
    p = svf * log1pf((float)cnt[i]);
    pop[i] = p;
  }
  float sq = p * p;
  for (int o = 32; o > 0; o >>= 1) sq += __shfl_down(sq, o);
  if ((threadIdx.x & 63) == 0) red[threadIdx.x >> 6] = sq;
  __syncthreads();
  if (threadIdx.x == 0) atomicAdd(nrm2, (double)(red[0] + red[1] + red[2] + red[3]));
}

__global__ __launch_bounds__(256) void pop_norm_kernel(float* __restrict__ pop,
                                                       const double* __restrict__ nrm2,
                                                       float* __restrict__ out) {
  int i = blockIdx.x * 256 + threadIdx.x;
  if (i < NUM_I) {
    float nrm = sqrtf((float)(*nrm2));
    float v = pop[i] / (nrm + 1e-8f);
    pop[i] = v;
    out[OFF_POP + i] = v;
  }
}

__global__ __launch_bounds__(256) void act_accum_kernel(const int* __restrict__ user,
                                                        const int* __restrict__ item,
                                                        const float* __restrict__ val, int n,
                                                        const float* __restrict__ pop,
                                                        ull* __restrict__ acc) {
  for (int k = blockIdx.x * 256 + threadIdx.x; k < n; k += gridDim.x * 256) {
    float term = val[k] / log1pf(pop[item[k]] + 1e-8f);
    atomicAdd(&acc[user[k]], (ull)llrintf(term * 16777216.0f));  // fixed-point 2^24
  }
}

__global__ __launch_bounds__(256) void act_pre_kernel(const ull* __restrict__ acc,
                                                      float* __restrict__ act,
                                                      double* __restrict__ nrm2) {
  __shared__ float red[4];
  int u = blockIdx.x * 256 + threadIdx.x;
  float a = 0.0f;
  if (u < NUM_U) {
    a = (float)((double)acc[u] * (1.0 / 16777216.0));
    act[u] = a;
  }
  float sq = a * a;
  for (int o = 32; o > 0; o >>= 1) sq += __shfl_down(sq, o);
  if ((threadIdx.x & 63) == 0) red[threadIdx.x >> 6] = sq;
  __syncthreads();
  if (threadIdx.x == 0) atomicAdd(nrm2, (double)(red[0] + red[1] + red[2] + red[3]));
}

__global__ __launch_bounds__(256) void act_norm_kernel(float* __restrict__ act,
                                                       const double* __restrict__ nrm2,
                                                       float* __restrict__ out) {
  int u = blockIdx.x * 256 + threadIdx.x;
  if (u < NUM_U) {
    float nrm = sqrtf((float)(*nrm2));
    float v = act[u] / (nrm + 1e-8f);
    act[u] = v;
    out[OFF_ACT + u] = v;
  }
}

// ---------------- bit tricks for touched-output bitmaps ----------------
// evencomp: pair-OR bits (2i,2i+1) -> bit i (low 16 of result)
__device__ inline uint32_t evencomp(uint32_t x) {
  x = (x | (x >> 1)) & 0x55555555u;
  x = (x | (x >> 1)) & 0x33333333u;
  x = (x | (x >> 2)) & 0x0F0F0F0Fu;
  x = (x | (x >> 4)) & 0x00FF00FFu;
  x = (x | (x >> 8)) & 0x0000FFFFu;
  return x;
}
// H word i over input bitmap B: H[32i+j] = B[64i+2j] | B[64i+2j+1]
template <int NWIN>
__device__ inline uint32_t hword(const uint32_t* B, int i) {
  uint32_t a = (2 * i < NWIN) ? B[2 * i] : 0u;
  uint32_t b = (2 * i + 1 < NWIN) ? B[2 * i + 1] : 0u;
  return evencomp(a) | (evencomp(b) << 16);
}
// touched-output word w: T[m] = H[m] | H[m-1] | H[m-2]
// (output m reads input cols [2m-4, 2m+1] = pairs m-2, m-1, m)
template <int NWIN>
__device__ inline uint32_t tword(const uint32_t* B, int w) {
  uint32_t h = hword<NWIN>(B, w);
  uint32_t hp = (w > 0) ? hword<NWIN>(B, w - 1) : 0u;
  return h | (h << 1) | (h << 2) | (hp >> 31) | (hp >> 30);
}

// One sparse in-place DWT level (levels 2-3). Tout = touched-output bitmap for
// THIS level (Tout bit m == window over input bitmap nonempty -- exact
// condition equivalence); Tin = this level's input bitmap (stale test).
// Batched read->barrier->write preserves the in-place safety proof and the
// per-thread position order (m = tid + 256j, j ascending). Skipped terms are
// exact +/-0.0 identities -> bit-identical results.
template <int MOUT, bool LAST>
__device__ inline void dwt_level_sparseT(float* __restrict__ buf,
                                         const uint32_t* __restrict__ Tout,
                                         const uint32_t* __restrict__ Tin,
                                         int tid, float& h_acc, float& lo_acc) {
  const uint32_t mbit = 1u << (tid & 31);
  for (int base = 0; base < MOUT; base += 2048) {
    float lov[8], hiv[8];
    int mv[8];
    bool comp[8], stale[8];
#pragma unroll
    for (int u = 0; u < 8; ++u) {
      int m = base + tid + (u << 8);
      bool ok = m < MOUT;
      mv[u] = m;
      int wi = ok ? (m >> 5) : 0;
      bool touched = ok && ((Tout[wi] & mbit) != 0u);
      comp[u] = touched;
      stale[u] = (!LAST) && ok && ((Tin[wi] & mbit) != 0u);
      lov[u] = 0.0f; hiv[u] = 0.0f;
      if (touched) {
        const float* s = buf + 2 * m + 5;   // s[-t] == data[2*m+1-t]
        float x0 = s[0], x1 = s[-1], x2 = s[-2], x3 = s[-3], x4 = s[-4], x5 = s[-5];
        float lo = 0.0f, hi = 0.0f;
        lo += 0.035226291882100656f * x0;  hi += -0.3326705529509569f * x0;
        lo += -0.08544127388224149f * x1;  hi += 0.8068915093133388f * x1;
        lo += -0.13501102001039084f * x2;  hi += -0.4598775021193313f * x2;
        lo += 0.4598775021193313f * x3;    hi += -0.13501102001039084f * x3;
        lo += 0.8068915093133388f * x4;    hi += 0.08544127388224149f * x4;
        lo += 0.3326705529509569f * x5;    hi += 0.035226291882100656f * x5;
        lov[u] = lo; hiv[u] = hi;
      }
    }
    if (!LAST) __syncthreads();
#pragma unroll
    for (int u = 0; u < 8; ++u) {
      if (comp[u]) {
        if (!LAST) buf[4 + mv[u]] = lov[u];
        else lo_acc += lov[u];
        h_acc += hiv[u] * hiv[u];
      } else if (stale[u]) {
        buf[4 + mv[u]] = 0.0f;   // clear stale input so next level reads +0.0
      }
    }
  }
}

// per-row 3-level db3 DWT stats. Dedup O(n) via bitmap-rank + atomicMax;
// all three levels use O(1) touched-output bit tests (T1/T2/T3).
template <int NCOLS, int M1, int M2, int M3, int CAP>
__global__ __launch_bounds__(256) void dwt_rows_kernel(
    const uint32_t* __restrict__ klist, const int* __restrict__ rowlen,
    const int* __restrict__ colsrc, const float* __restrict__ values,
    const float* __restrict__ scale_vec,
    float* __restrict__ low_out, float* __restrict__ high_out) {
  constexpr int NW = NCOLS / 32;        // col bitmap words
  constexpr int WPT = NW / 256;         // words per thread in the scan
  constexpr int NW1 = (M1 + 31) / 32;   // T1 words
  constexpr int NW2 = (M2 + 31) / 32;   // T2 words
  constexpr int NW3 = (M3 + 31) / 32;   // T3 words
  static_assert(NW1 + NW2 + NW3 <= 2 * CAP, "T1+T2+T3 must fit ecol+ek");
  static_assert(WPT * 256 == NW, "NW must be a multiple of 256");
  extern __shared__ float smem[];
  float* buf = smem;                          // M1+12 (data at +4)
  int* slot = (int*)(buf + (M1 + 12));        // CAP winner codes; sval aliases
  float* sval = (float*)slot;                 // CAP winner values (rank order)
  uint32_t* treg = (uint32_t*)(slot + CAP);   // 2*CAP: ecol+ek, then T1+T2+T3
  int* ecol = (int*)treg;                     // CAP staged cols
  int* ek = ecol + CAP;                       // CAP staged orig indices
  uint32_t* T1 = treg;                        // NW1 (alias, after dedup)
  uint32_t* T2 = treg + NW1;                  // NW2
  uint32_t* T3 = treg + NW1 + NW2;            // NW3
  uint32_t* bitmap = (uint32_t*)(ek + CAP);   // NW
  uint16_t* prefix = (uint16_t*)(bitmap + NW);// NW u16
  float* red = (float*)(prefix + NW);         // 16
  int* s_nw = (int*)(red + 16);               // 1

  const int r = blockIdx.x;
  const int tid = threadIdx.x;
  const float scale = 1.0f + scale_vec[r];
  int n = rowlen[r];
  if (n > CAP) n = CAP;

  // init (float4 buf zeroing)
  {
    constexpr int NB4 = (M1 + 12) / 4;
    float4 z; z.x = 0.0f; z.y = 0.0f; z.z = 0.0f; z.w = 0.0f;
    for (int i = tid; i < NB4; i += 256) ((float4*)buf)[i] = z;
    for (int i = NB4 * 4 + tid; i < M1 + 12; i += 256) buf[i] = 0.0f;
  }
  for (int i = tid; i < NW; i += 256) bitmap[i] = 0u;
  for (int i = tid; i < CAP; i += 256) slot[i] = 0;
  __syncthreads();

  // stage entries + column bitmap
  for (int e = tid; e < n; e += 256) {
    uint32_t k = klist[(size_t)r * CAP + e];
    int c = colsrc[k];
    ecol[e] = c;
    ek[e] = (int)k;
    atomicOr(&bitmap[c >> 5], 1u << (c & 31));
  }
  __syncthreads();

  // popcount prefix scan over bitmap words -> prefix[w] = #distinct cols < 32w
  {
    int v = 0;
#pragma unroll
    for (int j = 0; j < WPT; ++j) v += __popc(bitmap[tid * WPT + j]);
    int lane = tid & 63, wid = tid >> 6;
    int incl = v;
    for (int off = 1; off < 64; off <<= 1) {
      int y = __shfl_up(incl, off, 64);
      if (lane >= off) incl += y;
    }
    int* isc = (int*)red;
    if (lane == 63) isc[wid] = incl;
    __syncthreads();
    int base = 0;
    for (int ww = 0; ww < wid; ++ww) base += isc[ww];
    int run = base + incl - v;
#pragma unroll
    for (int j = 0; j < WPT; ++j) {
      prefix[tid * WPT + j] = (uint16_t)run;
      run += __popc(bitmap[tid * WPT + j]);
    }
    if (tid == 255) *s_nw = run;   // total distinct cols
  }
  __syncthreads();

  // O(n) dedup: rank(col) via bitmap+prefix, winner = max orig index k
  for (int e = tid; e < n; e += 256) {
    int c = ecol[e];
    int w = c >> 5;
    int rank = (int)prefix[w] + __popc(bitmap[w] & ((1u << (c & 31)) - 1u));
    atomicMax(&slot[rank], ek[e] + 1);
  }
  __syncthreads();
  const int nw_cnt = *s_nw;

  // compact winner values (slot -> sval in place) + build T1 (ecol/ek dead)
  for (int rr = tid; rr < nw_cnt; rr += 256) {
    int k = slot[rr] - 1;
    sval[rr] = values[k] * scale;
  }
  for (int w = tid; w < NW1; w += 256) T1[w] = tword<NW>(bitmap, w);
  __syncthreads();

  // ---- level 1: touched test via T1 bit; rank gather for touched ----
  const uint32_t mbit = 1u << (tid & 31);
  float h1 = 0.0f;
  for (int m = tid; m < M1; m += 256) {
    if ((T1[m >> 5] & mbit) == 0u) continue;
    int c0 = 2 * m - 4; c0 = c0 < 0 ? 0 : c0;
    int c1 = 2 * m + 1; c1 = c1 > NCOLS - 1 ? NCOLS - 1 : c1;
    int w0 = c0 >> 5, w1 = c1 >> 5;
    uint32_t b0 = bitmap[w0];
    uint32_t mlo = ~((1u << (c0 & 31)) - 1u);
    uint32_t mhi = (uint32_t)(((uint64_t)1u << ((c1 & 31) + 1)) - 1u);
    uint32_t sel0, sel1; uint32_t b1 = 0;
    if (w1 == w0) {
      sel0 = b0 & mlo & mhi;
      sel1 = 0u;
    } else {
      b1 = bitmap[w1];
      sel0 = b0 & mlo;
      sel1 = b1 & mhi;
    }
    float tv0 = 0.0f, tv1 = 0.0f, tv2 = 0.0f, tv3 = 0.0f, tv4 = 0.0f, tv5 = 0.0f;
    int tp1 = 2 * m + 1;
    uint32_t s = sel0;
    while (s) {
      int b = __ffs(s) - 1; s &= s - 1u;
      int c = (w0 << 5) + b;
      int idx = (int)prefix[w0] + __popc(b0 & ((1u << b) - 1u));
      float v = sval[idx];
      int t = tp1 - c;
      if (t == 0) tv0 = v; else if (t == 1) tv1 = v; else if (t == 2) tv2 = v;
      else if (t == 3) tv3 = v; else if (t == 4) tv4 = v; else tv5 = v;
    }
    s = sel1;
    while (s) {
      int b = __ffs(s) - 1; s &= s - 1u;
      int c = (w1 << 5) + b;
      int idx = (int)prefix[w1] + __popc(b1 & ((1u << b) - 1u));
      float v = sval[idx];
      int t = tp1 - c;
      if (t == 0) tv0 = v; else if (t == 1) tv1 = v; else if (t == 2) tv2 = v;
      else if (t == 3) tv3 = v; else if (t == 4) tv4 = v; else tv5 = v;
    }
    float lo = 0.0f, hi = 0.0f;
    lo += 0.035226291882100656f * tv0;  hi += -0.3326705529509569f * tv0;
    lo += -0.08544127388224149f * tv1;  hi += 0.8068915093133388f * tv1;
    lo += -0.13501102001039084f * tv2;  hi += -0.4598775021193313f * tv2;
    lo += 0.4598775021193313f * tv3;    hi += -0.13501102001039084f * tv3;
    lo += 0.8068915093133388f * tv4;    hi += 0.08544127388224149f * tv4;
    lo += 0.3326705529509569f * tv5;    hi += 0.035226291882100656f * tv5;
    buf[4 + m] = lo;
    h1 += hi * hi;
  }
  // build T2 from T1 (T1 complete as of the last barrier)
  for (int w = tid; w < NW2; w += 256) T2[w] = tword<NW1>(T1, w);
  __syncthreads();
  // build T3 from T2 (T2 complete; no reader of T3 until after level-2's
  // internal barriers + the explicit barrier below)
  for (int w = tid; w < NW3; w += 256) T3[w] = tword<NW2>(T2, w);

  // ---- sparse levels 2-3, in place over buf ----
  float h2 = 0.0f, h3 = 0.0f, slo = 0.0f;
  float dummy = 0.0f;
  dwt_level_sparseT<M2, false>(buf, T2, T1, tid, h2, dummy);
  __syncthreads();
  // zero the stale gap read by level 3 (data [M2 .. M2+7])
  if (tid < 8) buf[4 + M2 + tid] = 0.0f;
  __syncthreads();
  dwt_level_sparseT<M3, true>(buf, T3, T2, tid, h3, slo);

  for (int o = 32; o > 0; o >>= 1) {
    h1 += __shfl_down(h1, o);
    h2 += __shfl_down(h2, o);
    h3 += __shfl_down(h3, o);
    slo += __shfl_down(slo, o);
  }
  int w = tid >> 6, lane = tid & 63;
  if (lane == 0) { red[w] = h1; red[4 + w] = h2; red[8 + w] = h3; red[12 + w] = slo; }
  __syncthreads();
  if (tid == 0) {
    float s1 = red[0] + red[1] + red[2] + red[3];
    float s2 = red[4] + red[5] + red[6] + red[7];
    float s3 = red[8] + red[9] + red[10] + red[11];
    float sl = red[12] + red[13] + red[14] + red[15];
    low_out[r] = sl / (float)M3;
    high_out[r] = sqrtf(s1) + sqrtf(s2) + sqrtf(s3);
  }
}

__global__ __launch_bounds__(256) void beta_kernel(
    const float* __restrict__ u_low, const float* __restrict__ u_high,
    const float* __restrict__ i_low, const float* __restrict__ i_high,
    float* __restrict__ out, K2 kAu, K2 kBu, K2 kAi, K2 kBi) {
  int t = blockIdx.x * 256 + threadIdx.x;
  if (t >= NUM_U + NUM_I) return;
  float low, high;
  K2 ka, kb;
  int o0, o1;
  if (t < NUM_U) {
    low = u_low[t]; high = u_high[t];
    ka = elem_key(kAu, (uint32_t)t, (uint32_t)NUM_U);
    kb = elem_key(kBu, (uint32_t)t, (uint32_t)NUM_U);
    o0 = OFF_UPW + t; o1 = OFF_UMW + t;
  } else {
    int j = t - NUM_U;
    low = i_low[j]; high = i_high[j];
    ka = elem_key(kAi, (uint32_t)j, (uint32_t)NUM_I);
    kb = elem_key(kBi, (uint32_t)j, (uint32_t)NUM_I);
    o0 = OFF_IPW + j; o1 = OFF_IMW + j;
  }
  float a1 = fmaxf(low, 1e-6f);
  float a2 = fmaxf(high, 1e-6f);
  float s = a1 + a2;
  a1 = a1 / s;
  a2 = a2 / s;
  float lga = log_gamma_sample(ka, 10.0f * a1);
  float lgb = log_gamma_sample(kb, 10.0f * a2);
  float m = fmaxf(lga, lgb);
  float na = expf(lga - m);
  float nb = expf(lgb - m);
  float w = na / (na + nb);
  out[o0] = w;
  out[o1] = 1.0f - w;
}

// ---------------- host ----------------
extern "C" void kernel_launch(void* const* d_in, const int* in_sizes, int n_in,
                              void* d_out, int out_size, void* d_ws, size_t ws_size,
                              hipStream_t stream) {
  const int* user_idx = (const int*)d_in[0];
  const int* item_idx = (const int*)d_in[1];
  const float* values = (const float*)d_in[2];
  const int NNZ = in_sizes[0];

  char* ws = (char*)d_ws;
  double* nrm2_pop = (double*)(ws + 0);
  double* nrm2_act = (double*)(ws + 8);
  ull* sv_acc = (ull*)(ws + 16);
  ull* act_acc = (ull*)(ws + 65552);
  float* pop = (float*)(ws + 229392);
  float* act = (float*)(ws + 262160);
  int* fill_u = (int*)(ws + 327696);
  int* fill_i = (int*)(ws + 393232);
  float* u_low = (float*)(ws + 426000);
  float* u_high = (float*)(ws + 491536);
  float* i_low = (float*)(ws + 557072);
  float* i_high = (float*)(ws + 589840);
  uint32_t* klist_u = (uint32_t*)(ws + 622608);
  uint32_t* klist_i = (uint32_t*)(ws + 11108368);
  float* out = (float*)d_out;

  // host-side key derivation: root=key(42)=(0,42); ku,ki=split(root); then
  // (key_a,key_b)=split(k) inside beta for each side.
  K2 root; root.a = 0u; root.b = 42u;
  K2 ku, ki, kAu, kBu, kAi, kBi;
  split2(root, ku, ki);
  split2(ku, kAu, kBu);
  split2(ki, kAi, kBi);

  const int zero_words = 622608 / 8;
  zero_kernel<<<(zero_words + 255) / 256, 256, 0, stream>>>((ull*)ws, zero_words);
  count_fill_kernel<<<1024, 256, 0, stream>>>(user_idx, item_idx, values, NNZ,
                                              sv_acc, fill_u, fill_i, klist_u, klist_i);
  pop_raw_kernel<<<NUM_I / 256, 256, 0, stream>>>(fill_i, sv_acc, pop, nrm2_pop);
  pop_norm_kernel<<<NUM_I / 256, 256, 0, stream>>>(pop, nrm2_pop, out);
  act_accum_kernel<<<1024, 256, 0, stream>>>(user_idx, item_idx, values, NNZ, pop, act_acc);
  act_pre_kernel<<<NUM_U / 256, 256, 0, stream>>>(act_acc, act, nrm2_act);
  act_norm_kernel<<<NUM_U / 256, 256, 0, stream>>>(act, nrm2_act, out);

  // LDS words: buf(M1+12) + slot CAP + ecol/ek 2*CAP + bitmap NW + prefix NW/2 + red 16 + 1
  // users: 4110+160+320+256+128+16+1 = 4991 w = 19964 B -> 8 blocks/CU
  constexpr int U_SHM = ((4098 + 12) + 3 * CAP_U + 256 + 128 + 16 + 1) * 4;
  // items: 8206+256+512+512+256+16+1 = 9759 w = 39036 B -> 4 blocks/CU
  constexpr int I_SHM = ((8194 + 12) + 3 * CAP_I + 512 + 256 + 16 + 1) * 4;
  hipFuncSetAttribute((const void*)dwt_rows_kernel<8192, 4098, 2051, 1028, CAP_U>,
                      hipFuncAttributeMaxDynamicSharedMemorySize, U_SHM);
  hipFuncSetAttribute((const void*)dwt_rows_kernel<16384, 8194, 4099, 2052, CAP_I>,
                      hipFuncAttributeMaxDynamicSharedMemorySize, I_SHM);

  dwt_rows_kernel<8192, 4098, 2051, 1028, CAP_U><<<NUM_U, 256, U_SHM, stream>>>(
      klist_u, fill_u, item_idx, values, act, u_low, u_high);
  dwt_rows_kernel<16384, 8194, 4099, 2052, CAP_I><<<NUM_I, 256, I_SHM, stream>>>(
      klist_i, fill_i, user_idx, values, pop, i_low, i_high);

  beta_kernel<<<(NUM_U + NUM_I + 255) / 256, 256, 0, stream>>>(
      u_low, u_high, i_low, i_high, out, kAu, kBu, kAi, kBi);
}